// Round 14
// baseline (1080.318 us; speedup 1.0000x reference)
//
#include <hip/hip_runtime.h>
#include <math.h>

#define NX 8192
#define NY 65536
#define DIM 512
#define KNN 8

#define BM 256                 // Y rows per tile (MFMA M side)
#define BN 128                 // X rows per block (MFMA N side)
#define BK 32                  // K step (64-B LDS rows: naturally conflict-free)
#define COLS_PER_CHUNK 2048    // Y rows streamed per block
#define TILES (COLS_PER_CHUNK / BM)           // 8
#define KSTEPS (DIM / BK)      // 16 per tile
#define NSEG 8                 // Y segments (s>>3)
#define NZ 4                   // Y sub-segments (grid.z)
#define LPT 6                  // per-lane top-K (packed keys, branchless)
#define KEEP 8                 // kept per (row, slot)
#define NCAND (NSEG * NZ * KEEP)              // 256 per row (rescore unchanged)
#define RESC 32                // rescored per row

typedef short bf16x8 __attribute__((ext_vector_type(8)));
typedef float f32x4 __attribute__((ext_vector_type(4)));

#define AS1(p) (const __attribute__((address_space(1))) void*)(p)
#define AS3(p) (__attribute__((address_space(3))) void*)(p)

__device__ __forceinline__ unsigned short f2b(float f) {
    unsigned int u = __float_as_uint(f);
    u += 0x7FFFu + ((u >> 16) & 1u);       // RNE to bf16
    return (unsigned short)(u >> 16);
}

__device__ __forceinline__ unsigned int umin_(unsigned int a, unsigned int b) { return a < b ? a : b; }
__device__ __forceinline__ unsigned int umax_(unsigned int a, unsigned int b) { return a > b ? a : b; }

// branchless sorted-insert (ascending): 2 VALU ops/slot, no divergence.
template <int K>
__device__ __forceinline__ void pushk_b(unsigned int x, unsigned int (&l)[K]) {
    unsigned int prev = l[0];
    l[0] = umin_(l[0], x);
#pragma unroll
    for (int i = 1; i < K; ++i) {
        unsigned int cur = l[i];
        l[i] = umin_(umax_(x, prev), cur);
        prev = cur;
    }
}

// branchy insert (serial contexts: cheap reject dominates)
template <int K>
__device__ __forceinline__ void pushk(unsigned int k, unsigned int (&lst)[K]) {
    if (k >= lst[K - 1]) return;
    lst[K - 1] = k;
#pragma unroll
    for (int p = K - 1; p > 0; --p) {
        if (lst[p] < lst[p - 1]) {
            unsigned int t = lst[p]; lst[p] = lst[p - 1]; lst[p - 1] = t;
        }
    }
}

template <int K>
__device__ __forceinline__ void push(float d, int gi, float (&bd)[K], int (&bi)[K]) {
    if (d > bd[K - 1] || (d == bd[K - 1] && gi >= bi[K - 1])) return;
    bd[K - 1] = d; bi[K - 1] = gi;
#pragma unroll
    for (int p = K - 1; p > 0; --p) {
        bool sw = (bd[p] < bd[p - 1]) || (bd[p] == bd[p - 1] && bi[p] < bi[p - 1]);
        if (sw) {
            float td = bd[p]; bd[p] = bd[p - 1]; bd[p - 1] = td;
            int   ti = bi[p]; bi[p] = bi[p - 1]; bi[p - 1] = ti;
        }
    }
}

__global__ void cvt_bf16_kernel(const float* __restrict__ src,
                                unsigned short* __restrict__ dst, int n8) {
    int i = blockIdx.x * blockDim.x + threadIdx.x;
    if (i >= n8) return;
    const float4* s = (const float4*)src;
    float4 a0 = s[i * 2], a1 = s[i * 2 + 1];
    bf16x8 h;
    h[0] = (short)f2b(a0.x); h[1] = (short)f2b(a0.y);
    h[2] = (short)f2b(a0.z); h[3] = (short)f2b(a0.w);
    h[4] = (short)f2b(a1.x); h[5] = (short)f2b(a1.y);
    h[6] = (short)f2b(a1.z); h[7] = (short)f2b(a1.w);
    *(bf16x8*)(dst + (size_t)i * 8) = h;
}

__global__ void ysq_kernel(const float* __restrict__ Y, float* __restrict__ ysq) {
    int row  = (blockIdx.x * blockDim.x + threadIdx.x) >> 6;
    int lane = threadIdx.x & 63;
    if (row >= NY) return;
    const float4* yr = reinterpret_cast<const float4*>(Y + (size_t)row * DIM);
    double s = 0.0;
#pragma unroll
    for (int i = 0; i < 2; ++i) {
        float4 v = yr[lane + 64 * i];
        s += (double)v.x * v.x + (double)v.y * v.y + (double)v.z * v.z + (double)v.w * v.w;
    }
#pragma unroll
    for (int off = 32; off > 0; off >>= 1) s += __shfl_xor(s, off, 64);
    if (lane == 0) ysq[row] = (float)s;
}

// Coarse: 256x128 block, 4 waves of 128x64, BK=32 (64-B LDS rows, no swizzle
// needed), dbuf, one barrier per K-step, branchless top-6 lane lists.
__global__ __launch_bounds__(256, 2) void knn_coarse_fast(
        const unsigned short* __restrict__ Xb, const unsigned short* __restrict__ Yb,
        const float* __restrict__ ysq,
        unsigned int* __restrict__ cand_k) {
    // [0,32K) As dbuf = 2 x [256 rows][64 B] Y tiles;
    // [32K,48K) Bs dbuf = 2 x [128 rows][64 B] X tiles;
    // [48K,56K) ysq_s (x32-scaled, whole chunk). Merge reuses [0,25.6K).
    __shared__ __align__(16) char smem[57344];
    char* As = smem;
    char* Bs = smem + 32768;
    float* ysq_s = (float*)(smem + 49152);

    const int tid  = threadIdx.x;
    const int lane = tid & 63;
    const int w    = tid >> 6;
    const int l15  = lane & 15;
    const int lg   = lane >> 4;              // 0..3
    const int xcd  = blockIdx.x;             // 0..7 (linear%8 == blockIdx.x)
    const int s_   = blockIdx.y;             // 0..63
    const int z    = blockIdx.z;             // 0..3
    const int row0  = (xcd * 8 + (s_ & 7)) * BN;   // X tile (8 per XCD resident)
    const int yseg  = s_ >> 3;               // 0..7
    const int ybase = yseg * (NY / NSEG) + z * COLS_PER_CHUNK;
    const int slot  = yseg * NZ + z;         // 0..31 candidate slot
    const int m0 = (w >> 1) * 128;           // wave quadrant: Y side (2)
    const int n0 = (w & 1) * 64;             //                X side (2)

    // ysq for the whole chunk -> LDS, pre-scaled by 32 (broadcast reads later)
#pragma unroll
    for (int i = 0; i < 2; ++i) {
        float4 v = *(const float4*)(ysq + ybase + tid * 8 + i * 4);
        float4 sv = {v.x * 32.f, v.y * 32.f, v.z * 32.f, v.w * 32.f};
        *(float4*)(ysq_s + tid * 8 + i * 4) = sv;
    }
    __syncthreads();

    // staging geometry: lane covers 16 B of a 64-B row: row += lane>>2,
    // byte (lane&3)*16. 6 insts/wave/K-step (4 A + 2 B).
    const int srow = lane >> 2;                     // 0..15
    const int scb  = (lane & 3) << 4;               // 0,16,32,48
    const char* pXbase = (const char*)Xb
        + ((size_t)(row0 + w * 32 + srow) << 10) + scb;

#define STAGE(tt, kcc, buf)                                                      \
    {                                                                            \
        const char* pY_ = (const char*)Yb                                        \
            + ((size_t)(ybase + (tt) * BM + w * 64 + srow) << 10)                \
            + ((kcc) << 6) + scb;                                                \
        const char* pX_ = pXbase + ((kcc) << 6);                                 \
        char* dA_ = As + ((buf) << 14) + (w << 12);                              \
        char* dB_ = Bs + ((buf) << 13) + (w << 11);                              \
        _Pragma("unroll")                                                        \
        for (int q = 0; q < 4; ++q)                                              \
            __builtin_amdgcn_global_load_lds(AS1(pY_ + ((size_t)(q * 16) << 10)),\
                                             AS3(dA_ + (q << 10)), 16, 0, 0);    \
        _Pragma("unroll")                                                        \
        for (int q = 0; q < 2; ++q)                                              \
            __builtin_amdgcn_global_load_lds(AS1(pX_ + ((size_t)(q * 16) << 10)),\
                                             AS3(dB_ + (q << 10)), 16, 0, 0);    \
    }

    unsigned int kb_[4][LPT];
#pragma unroll
    for (int nf = 0; nf < 4; ++nf)
#pragma unroll
        for (int m = 0; m < LPT; ++m) kb_[nf][m] = 0xffffffffu;

    STAGE(0, 0, 0);   // prologue: 6 loads in flight

    for (int t = 0; t < TILES; ++t) {
        f32x4 acc[8][4];
#pragma unroll
        for (int i = 0; i < 8; ++i)
#pragma unroll
            for (int j = 0; j < 4; ++j) acc[i][j] = (f32x4){0.f, 0.f, 0.f, 0.f};

#pragma unroll
        for (int kc = 0; kc < KSTEPS; ++kc) {
            const int buf = kc & 1;
            asm volatile("s_waitcnt vmcnt(0)" ::: "memory");
            __builtin_amdgcn_sched_barrier(0);
            __builtin_amdgcn_s_barrier();
            if (kc < KSTEPS - 1) {
                STAGE(t, kc + 1, buf ^ 1);
            } else if (t + 1 < TILES) {
                STAGE(t + 1, 0, buf ^ 1);
            }

            const char* Ab = As + (buf << 14);
            const char* Bb = Bs + (buf << 13);
            bf16x8 bfr[4];
#pragma unroll
            for (int nf = 0; nf < 4; ++nf)
                bfr[nf] = *(const bf16x8*)(Bb + ((n0 + nf * 16 + l15) << 6) + lg * 16);
            __builtin_amdgcn_s_setprio(1);
#pragma unroll
            for (int mf = 0; mf < 8; ++mf) {
                bf16x8 af = *(const bf16x8*)(Ab + ((m0 + mf * 16 + l15) << 6) + lg * 16);
#pragma unroll
                for (int nf = 0; nf < 4; ++nf)
                    acc[mf][nf] = __builtin_amdgcn_mfma_f32_16x16x32_bf16(
                        af, bfr[nf], acc[mf][nf], 0, 0, 0);
            }
            __builtin_amdgcn_s_setprio(0);
        }

        // epilogue: keys = (trunc(32*ysq - 64*dot) << 16) | yi, branchless insert
#pragma unroll
        for (int mf = 0; mf < 8; ++mf) {
            const int lrow = t * BM + m0 + mf * 16 + lg * 4;   // chunk-local
            const int gib  = ybase + lrow;
            const float4 yq32 = *(const float4*)(ysq_s + lrow); // broadcast
            float yv[4] = {yq32.x, yq32.y, yq32.z, yq32.w};
#pragma unroll
            for (int nf = 0; nf < 4; ++nf) {
#pragma unroll
                for (int j = 0; j < 4; ++j) {
                    float d32 = fmaf(acc[mf][nf][j], -64.f, yv[j]);
                    d32 = fminf(fmaxf(d32, 0.f), 65535.f);
                    pushk_b<LPT>(((unsigned int)d32 << 16) | (unsigned int)(gib + j),
                                 kb_[nf]);
                }
            }
        }
    }
#undef STAGE

    // ---- merge 8 lane-lists per X row (2 waves x 4 lg per row) ----
    __syncthreads();
    unsigned int* mbuf = (unsigned int*)smem;   // 128 rows x 50 dwords = 25.6 KB
    const int mslot = (w >> 1) * 4 + lg;        // 0..7
#pragma unroll
    for (int nf = 0; nf < 4; ++nf) {
        const int r = n0 + nf * 16 + l15;
#pragma unroll
        for (int e = 0; e < LPT; ++e)
            mbuf[r * 50 + mslot * LPT + e] = kb_[nf][e];
    }
    __syncthreads();
    if (tid < 128) {
        unsigned int mk[KEEP];
#pragma unroll
        for (int m = 0; m < KEEP; ++m) mk[m] = 0xffffffffu;
        for (int s2 = 0; s2 < 8; ++s2)
#pragma unroll
            for (int e = 0; e < LPT; ++e)
                pushk_b<KEEP>(mbuf[tid * 50 + s2 * LPT + e], mk);
        const int row = row0 + tid;
        unsigned int* co = cand_k + (size_t)row * NCAND + slot * KEEP;
#pragma unroll
        for (int m = 0; m < KEEP; ++m) co[m] = mk[m];
    }
}

// Rescore: coarse top-32 of 256 packed keys, then BIT-EXACT round-1 arithmetic.
__global__ __launch_bounds__(256) void knn_rescore(
        const float* __restrict__ X, const float* __restrict__ Y,
        const float* __restrict__ ysq,
        const unsigned int* __restrict__ cand_k,
        int* __restrict__ out) {
    __shared__ unsigned int ck[8][NCAND];
    __shared__ int   rci[8][RESC];
    __shared__ float rd[8][RESC];

    const int tid  = threadIdx.x;
    const int row0 = blockIdx.x * 8;

#pragma unroll
    for (int q = 0; q < 8; ++q) {
        const int idx = q * 256 + tid;       // 0..2047
        const int r = idx >> 8, j = idx & 255;
        ck[r][j] = cand_k[(size_t)(row0 + r) * NCAND + j];
    }
    __syncthreads();

    if (tid < 8) {
        unsigned int mk[RESC];
#pragma unroll
        for (int m = 0; m < RESC; ++m) mk[m] = 0xffffffffu;
        for (int j = 0; j < NCAND; ++j) pushk<RESC>(ck[tid][j], mk);
#pragma unroll
        for (int m = 0; m < RESC; ++m) rci[tid][m] = (int)(mk[m] & 0xffffu);
    }
    __syncthreads();

    {
        const int r = tid >> 5, c = tid & 31;
        const int row = row0 + r;
        const int yi = rci[r][c];
        const float* xr = X + (size_t)row * DIM;
        const float* yr = Y + (size_t)yi * DIM;
        double acc64 = 0.0;
        for (int kc = 0; kc < DIM; kc += 64) {
            float acc = 0.f;
#pragma unroll
            for (int k4 = 0; k4 < 16; ++k4) {
                float4 xv = *(const float4*)(xr + kc + k4 * 4);
                float4 yv = *(const float4*)(yr + kc + k4 * 4);
                acc = fmaf(xv.x, yv.x, acc);
                acc = fmaf(xv.y, yv.y, acc);
                acc = fmaf(xv.z, yv.z, acc);
                acc = fmaf(xv.w, yv.w, acc);
            }
            acc64 += (double)acc;
        }
        rd[r][c] = (float)((double)ysq[yi] - 2.0 * acc64);
    }
    __syncthreads();

    if (tid < 8) {
        float fd[KNN]; int fi[KNN];
#pragma unroll
        for (int m = 0; m < KNN; ++m) { fd[m] = INFINITY; fi[m] = 0x7fffffff; }
        for (int j = 0; j < RESC; ++j) push<KNN>(rd[tid][j], rci[tid][j], fd, fi);
        const int row = row0 + tid;
#pragma unroll
        for (int m = 0; m < KNN; ++m) out[row * KNN + m] = fi[m];
    }
}

extern "C" void kernel_launch(void* const* d_in, const int* in_sizes, int n_in,
                              void* d_out, int out_size, void* d_ws, size_t ws_size,
                              hipStream_t stream) {
    const float* X = (const float*)d_in[0];   // [8192, 512]
    const float* Y = (const float*)d_in[1];   // [65536, 512]
    int* out = (int*)d_out;                   // [8192, 8] int32

    char* ws = (char*)d_ws;
    float* ysq           = (float*)ws;                              // 256 KB
    unsigned int* cand_k = (unsigned int*)(ws + 262144);            // 8 MB
    size_t off = 262144 + (size_t)NX * NCAND * 4;
    unsigned short* Xbf = (unsigned short*)(ws + off);              // 8 MB
    unsigned short* Ybf = (unsigned short*)(ws + off + (size_t)NX * DIM * 2);  // 64 MB

    ysq_kernel<<<NY / 4, 256, 0, stream>>>(Y, ysq);
    cvt_bf16_kernel<<<(NX * DIM / 8) / 256, 256, 0, stream>>>(X, Xbf, NX * DIM / 8);
    cvt_bf16_kernel<<<(NY * DIM / 8) / 256, 256, 0, stream>>>(Y, Ybf, NY * DIM / 8);

    dim3 g1(8, 64, NZ);   // 2048 blocks; linear%8 = blockIdx.x = xcd
    knn_coarse_fast<<<g1, 256, 0, stream>>>(Xbf, Ybf, ysq, cand_k);

    knn_rescore<<<NX / 8, 256, 0, stream>>>(X, Y, ysq, cand_k, out);
}

// Round 15
// 808.451 us; speedup vs baseline: 1.3363x; 1.3363x over previous
//
#include <hip/hip_runtime.h>
#include <math.h>

#define NX 8192
#define NY 65536
#define DIM 512
#define KNN 8

#define BM 128                 // Y rows per tile (MFMA M side)
#define BN 128                 // X rows per block (MFMA N side)
#define COLS_PER_CHUNK 2048    // Y rows streamed per block
#define TILES (COLS_PER_CHUNK / BM)           // 16
#define NSEG 8                 // Y segments (s>>3)
#define NZ 4                   // Y sub-segments (grid.z)
#define LPT 6                  // per-lane top-K (packed keys, branchless)
#define KEEP 8                 // kept per (row, slot)
#define NCAND (NSEG * NZ * KEEP)              // 256 per row (rescore unchanged)
#define RESC 32                // rescored per row

typedef short bf16x8 __attribute__((ext_vector_type(8)));
typedef short bf16x4 __attribute__((ext_vector_type(4)));
typedef float f32x4 __attribute__((ext_vector_type(4)));

#define AS1(p) (const __attribute__((address_space(1))) void*)(p)
#define AS3(p) (__attribute__((address_space(3))) void*)(p)

__device__ __forceinline__ unsigned short f2b(float f) {
    unsigned int u = __float_as_uint(f);
    u += 0x7FFFu + ((u >> 16) & 1u);       // RNE to bf16
    return (unsigned short)(u >> 16);
}

__device__ __forceinline__ unsigned int umin_(unsigned int a, unsigned int b) { return a < b ? a : b; }

// branchless sorted-insert (ascending): 1 min + (K-1) med3, no divergence.
// Identity: for prev <= cur, min(max(x,prev),cur) == median(x,prev,cur).
template <int K>
__device__ __forceinline__ void pushk_b(unsigned int x, unsigned int (&l)[K]) {
    unsigned int prev = l[0];
    l[0] = umin_(l[0], x);
#pragma unroll
    for (int i = 1; i < K; ++i) {
        unsigned int cur = l[i];
        unsigned int m;
        asm("v_med3_u32 %0, %1, %2, %3" : "=v"(m) : "v"(x), "v"(prev), "v"(cur));
        l[i] = m;
        prev = cur;
    }
}

// branchy insert (serial contexts: cheap reject dominates)
template <int K>
__device__ __forceinline__ void pushk(unsigned int k, unsigned int (&lst)[K]) {
    if (k >= lst[K - 1]) return;
    lst[K - 1] = k;
#pragma unroll
    for (int p = K - 1; p > 0; --p) {
        if (lst[p] < lst[p - 1]) {
            unsigned int t = lst[p]; lst[p] = lst[p - 1]; lst[p - 1] = t;
        }
    }
}

template <int K>
__device__ __forceinline__ void push(float d, int gi, float (&bd)[K], int (&bi)[K]) {
    if (d > bd[K - 1] || (d == bd[K - 1] && gi >= bi[K - 1])) return;
    bd[K - 1] = d; bi[K - 1] = gi;
#pragma unroll
    for (int p = K - 1; p > 0; --p) {
        bool sw = (bd[p] < bd[p - 1]) || (bd[p] == bd[p - 1] && bi[p] < bi[p - 1]);
        if (sw) {
            float td = bd[p]; bd[p] = bd[p - 1]; bd[p - 1] = td;
            int   ti = bi[p]; bi[p] = bi[p - 1]; bi[p - 1] = ti;
        }
    }
}

__global__ void cvt_bf16_kernel(const float* __restrict__ src,
                                unsigned short* __restrict__ dst, int n8) {
    int i = blockIdx.x * blockDim.x + threadIdx.x;
    if (i >= n8) return;
    const float4* s = (const float4*)src;
    float4 a0 = s[i * 2], a1 = s[i * 2 + 1];
    bf16x8 h;
    h[0] = (short)f2b(a0.x); h[1] = (short)f2b(a0.y);
    h[2] = (short)f2b(a0.z); h[3] = (short)f2b(a0.w);
    h[4] = (short)f2b(a1.x); h[5] = (short)f2b(a1.y);
    h[6] = (short)f2b(a1.z); h[7] = (short)f2b(a1.w);
    *(bf16x8*)(dst + (size_t)i * 8) = h;
}

// Fused: ||y||^2 (fp64, EXACT same summation order as the verified ysq_kernel)
// + bf16 convert/store. One wave per Y row.
__global__ void ysq_cvt_kernel(const float* __restrict__ Y,
                               float* __restrict__ ysq,
                               unsigned short* __restrict__ Yb) {
    int row  = (blockIdx.x * blockDim.x + threadIdx.x) >> 6;
    int lane = threadIdx.x & 63;
    if (row >= NY) return;
    const float4* yr = reinterpret_cast<const float4*>(Y + (size_t)row * DIM);
    unsigned short* dst = Yb + (size_t)row * DIM;
    double s = 0.0;
#pragma unroll
    for (int i = 0; i < 2; ++i) {
        float4 v = yr[lane + 64 * i];
        s += (double)v.x * v.x + (double)v.y * v.y + (double)v.z * v.z + (double)v.w * v.w;
        bf16x4 h;
        h[0] = (short)f2b(v.x); h[1] = (short)f2b(v.y);
        h[2] = (short)f2b(v.z); h[3] = (short)f2b(v.w);
        *(bf16x4*)(dst + i * 256 + lane * 4) = h;
    }
#pragma unroll
    for (int off = 32; off > 0; off >>= 1) s += __shfl_xor(s, off, 64);
    if (lane == 0) ysq[row] = (float)s;
}

// Coarse: r13 kernel (128x128 tile, dbuf, one barrier/K-step, X/Y L2 remap,
// branchless top-6) + med3 insert + cvt-saturation clamp (r15).
__global__ __launch_bounds__(256, 2) void knn_coarse_fast(
        const unsigned short* __restrict__ Xb, const unsigned short* __restrict__ Yb,
        const float* __restrict__ ysq,
        unsigned int* __restrict__ cand_k) {
    __shared__ __align__(16) char smem[65536];
    char* As = smem;
    char* Bs = smem + 32768;

    const int tid  = threadIdx.x;
    const int lane = tid & 63;
    const int w    = tid >> 6;
    const int l15  = lane & 15;
    const int lg   = lane >> 4;              // 0..3
    const int xcd  = blockIdx.x;             // 0..7 (linear%8 == blockIdx.x)
    const int s_   = blockIdx.y;             // 0..63
    const int z    = blockIdx.z;             // 0..3
    const int row0  = (xcd * 8 + (s_ & 7)) * BN;   // X tile (8 per XCD resident)
    const int yseg  = s_ >> 3;               // 0..7
    const int ybase = yseg * (NY / NSEG) + z * COLS_PER_CHUNK;
    const int slot  = yseg * NZ + z;         // 0..31 candidate slot
    const int m0 = (w >> 1) * 64;            // wave quadrant: Y side
    const int n0 = (w & 1) * 64;             //                X side

    const int srow = lane >> 3;                     // 0..7
    const int scb  = ((lane & 7) ^ srow) << 4;      // swizzled source chunk
    const char* pXbase = (const char*)Xb
        + ((size_t)(row0 + w * 32 + srow) << 10) + scb;

#define STAGE(tt, kcc, buf)                                                      \
    {                                                                            \
        const char* pY_ = (const char*)Yb                                        \
            + ((size_t)(ybase + (tt) * BM + w * 32 + srow) << 10)                \
            + ((kcc) << 7) + scb;                                                \
        const char* pX_ = pXbase + ((kcc) << 7);                                 \
        char* dA_ = As + ((buf) << 14) + (w << 12);                              \
        char* dB_ = Bs + ((buf) << 14) + (w << 12);                              \
        _Pragma("unroll")                                                        \
        for (int q = 0; q < 4; ++q) {                                            \
            __builtin_amdgcn_global_load_lds(AS1(pY_ + ((size_t)(q * 8) << 10)), \
                                             AS3(dA_ + (q << 10)), 16, 0, 0);    \
            __builtin_amdgcn_global_load_lds(AS1(pX_ + ((size_t)(q * 8) << 10)), \
                                             AS3(dB_ + (q << 10)), 16, 0, 0);    \
        }                                                                        \
    }

    unsigned int kb_[4][LPT];
#pragma unroll
    for (int nf = 0; nf < 4; ++nf)
#pragma unroll
        for (int m = 0; m < LPT; ++m) kb_[nf][m] = 0xffffffffu;

    STAGE(0, 0, 0);   // prologue: 8 loads in flight

    for (int t = 0; t < TILES; ++t) {
        const int ytile0 = ybase + t * BM;

        // ysq for the epilogue (asm: stays in our FIFO; drained by kc=1 vmcnt(0))
        f32x4 yv0, yv1, yv2, yv3;
        {
            const float* yp = ysq + ytile0 + m0 + lg * 4;
            asm volatile("global_load_dwordx4 %0, %1, off" : "=v"(yv0) : "v"(yp));
            asm volatile("global_load_dwordx4 %0, %1, off" : "=v"(yv1) : "v"(yp + 16));
            asm volatile("global_load_dwordx4 %0, %1, off" : "=v"(yv2) : "v"(yp + 32));
            asm volatile("global_load_dwordx4 %0, %1, off" : "=v"(yv3) : "v"(yp + 48));
        }

        f32x4 acc[4][4];
#pragma unroll
        for (int i = 0; i < 4; ++i)
#pragma unroll
            for (int j = 0; j < 4; ++j) acc[i][j] = (f32x4){0.f, 0.f, 0.f, 0.f};

#pragma unroll
        for (int kc = 0; kc < 8; ++kc) {
            const int buf = kc & 1;
            if (kc == 0) asm volatile("s_waitcnt vmcnt(4)" ::: "memory");
            else         asm volatile("s_waitcnt vmcnt(0)" ::: "memory");
            __builtin_amdgcn_sched_barrier(0);
            __builtin_amdgcn_s_barrier();
            if (kc < 7) {
                STAGE(t, kc + 1, buf ^ 1);
            } else if (t + 1 < TILES) {
                STAGE(t + 1, 0, buf ^ 1);
            }

            const char* Ab = As + (buf << 14);
            const char* Bb = Bs + (buf << 14);
#pragma unroll
            for (int kk = 0; kk < 2; ++kk) {
                const int kbyte = kk * 64 + lg * 16;
                const int sw = kbyte ^ ((l15 & 7) << 4);
                bf16x8 af[4], bf[4];
#pragma unroll
                for (int mf = 0; mf < 4; ++mf)
                    af[mf] = *(const bf16x8*)(Ab + ((m0 + mf * 16 + l15) << 7) + sw);
#pragma unroll
                for (int nf = 0; nf < 4; ++nf)
                    bf[nf] = *(const bf16x8*)(Bb + ((n0 + nf * 16 + l15) << 7) + sw);
                __builtin_amdgcn_s_setprio(1);
#pragma unroll
                for (int mf = 0; mf < 4; ++mf)
#pragma unroll
                    for (int nf = 0; nf < 4; ++nf)
                        acc[mf][nf] = __builtin_amdgcn_mfma_f32_16x16x32_bf16(
                            af[mf], bf[nf], acc[mf][nf], 0, 0, 0);
                __builtin_amdgcn_s_setprio(0);
            }
        }

        // epilogue: key = (sat_u32(min(32*ysq - 64*dot, 65535)) << 16) | yi
        // (v_cvt_u32_f32 clamps negatives to 0 in HW -> fmaxf dropped)
#pragma unroll
        for (int mf = 0; mf < 4; ++mf) {
            const int gib = ytile0 + m0 + mf * 16 + lg * 4;
            const f32x4 yv = (mf == 0) ? yv0 : (mf == 1) ? yv1 : (mf == 2) ? yv2 : yv3;
#pragma unroll
            for (int nf = 0; nf < 4; ++nf) {
#pragma unroll
                for (int j = 0; j < 4; ++j) {
                    float d32 = fmaf(acc[mf][nf][j], -64.f, yv[j] * 32.f);
                    d32 = fminf(d32, 65535.f);
                    unsigned int u;
                    asm("v_cvt_u32_f32 %0, %1" : "=v"(u) : "v"(d32));
                    pushk_b<LPT>((u << 16) | (unsigned int)(gib + j), kb_[nf]);
                }
            }
        }
    }
#undef STAGE

    // ---- merge 8 lane-lists per X row (reuses smem) ----
    __syncthreads();
    unsigned int* mbuf = (unsigned int*)smem;   // 128 rows x 50 dwords = 25.6 KB
    const int mslot = (w >> 1) * 4 + lg;        // 0..7
#pragma unroll
    for (int nf = 0; nf < 4; ++nf) {
        const int r = n0 + nf * 16 + l15;
#pragma unroll
        for (int e = 0; e < LPT; ++e)
            mbuf[r * 50 + mslot * LPT + e] = kb_[nf][e];
    }
    __syncthreads();
    if (tid < 128) {
        unsigned int mk[KEEP];
#pragma unroll
        for (int m = 0; m < KEEP; ++m) mk[m] = 0xffffffffu;
        for (int s2 = 0; s2 < 8; ++s2)
#pragma unroll
            for (int e = 0; e < LPT; ++e)
                pushk_b<KEEP>(mbuf[tid * 50 + s2 * LPT + e], mk);
        const int row = row0 + tid;
        unsigned int* co = cand_k + (size_t)row * NCAND + slot * KEEP;
#pragma unroll
        for (int m = 0; m < KEEP; ++m) co[m] = mk[m];
    }
}

// Rescore: coarse top-32 of 256 packed keys, then BIT-EXACT round-1 arithmetic.
__global__ __launch_bounds__(256) void knn_rescore(
        const float* __restrict__ X, const float* __restrict__ Y,
        const float* __restrict__ ysq,
        const unsigned int* __restrict__ cand_k,
        int* __restrict__ out) {
    __shared__ unsigned int ck[8][NCAND];
    __shared__ int   rci[8][RESC];
    __shared__ float rd[8][RESC];

    const int tid  = threadIdx.x;
    const int row0 = blockIdx.x * 8;

#pragma unroll
    for (int q = 0; q < 8; ++q) {
        const int idx = q * 256 + tid;       // 0..2047
        const int r = idx >> 8, j = idx & 255;
        ck[r][j] = cand_k[(size_t)(row0 + r) * NCAND + j];
    }
    __syncthreads();

    if (tid < 8) {
        unsigned int mk[RESC];
#pragma unroll
        for (int m = 0; m < RESC; ++m) mk[m] = 0xffffffffu;
        for (int j = 0; j < NCAND; ++j) pushk<RESC>(ck[tid][j], mk);
#pragma unroll
        for (int m = 0; m < RESC; ++m) rci[tid][m] = (int)(mk[m] & 0xffffu);
    }
    __syncthreads();

    {
        const int r = tid >> 5, c = tid & 31;
        const int row = row0 + r;
        const int yi = rci[r][c];
        const float* xr = X + (size_t)row * DIM;
        const float* yr = Y + (size_t)yi * DIM;
        double acc64 = 0.0;
        for (int kc = 0; kc < DIM; kc += 64) {
            float acc = 0.f;
#pragma unroll
            for (int k4 = 0; k4 < 16; ++k4) {
                float4 xv = *(const float4*)(xr + kc + k4 * 4);
                float4 yv = *(const float4*)(yr + kc + k4 * 4);
                acc = fmaf(xv.x, yv.x, acc);
                acc = fmaf(xv.y, yv.y, acc);
                acc = fmaf(xv.z, yv.z, acc);
                acc = fmaf(xv.w, yv.w, acc);
            }
            acc64 += (double)acc;
        }
        rd[r][c] = (float)((double)ysq[yi] - 2.0 * acc64);
    }
    __syncthreads();

    if (tid < 8) {
        float fd[KNN]; int fi[KNN];
#pragma unroll
        for (int m = 0; m < KNN; ++m) { fd[m] = INFINITY; fi[m] = 0x7fffffff; }
        for (int j = 0; j < RESC; ++j) push<KNN>(rd[tid][j], rci[tid][j], fd, fi);
        const int row = row0 + tid;
#pragma unroll
        for (int m = 0; m < KNN; ++m) out[row * KNN + m] = fi[m];
    }
}

extern "C" void kernel_launch(void* const* d_in, const int* in_sizes, int n_in,
                              void* d_out, int out_size, void* d_ws, size_t ws_size,
                              hipStream_t stream) {
    const float* X = (const float*)d_in[0];   // [8192, 512]
    const float* Y = (const float*)d_in[1];   // [65536, 512]
    int* out = (int*)d_out;                   // [8192, 8] int32

    char* ws = (char*)d_ws;
    float* ysq           = (float*)ws;                              // 256 KB
    unsigned int* cand_k = (unsigned int*)(ws + 262144);            // 8 MB
    size_t off = 262144 + (size_t)NX * NCAND * 4;
    unsigned short* Xbf = (unsigned short*)(ws + off);              // 8 MB
    unsigned short* Ybf = (unsigned short*)(ws + off + (size_t)NX * DIM * 2);  // 64 MB

    ysq_cvt_kernel<<<NY / 4, 256, 0, stream>>>(Y, ysq, Ybf);
    cvt_bf16_kernel<<<(NX * DIM / 8) / 256, 256, 0, stream>>>(X, Xbf, NX * DIM / 8);

    dim3 g1(8, 64, NZ);   // 2048 blocks; linear%8 = blockIdx.x = xcd
    knn_coarse_fast<<<g1, 256, 0, stream>>>(Xbf, Ybf, ysq, cand_k);

    knn_rescore<<<NX / 8, 256, 0, stream>>>(X, Y, ysq, cand_k, out);
}

// Round 16
// 536.823 us; speedup vs baseline: 2.0124x; 1.5060x over previous
//
#include <hip/hip_runtime.h>
#include <math.h>

#define NX 8192
#define NY 65536
#define DIM 512
#define KNN 8

#define BM 128                 // Y rows per tile (MFMA M side)
#define BN 128                 // X rows per block (MFMA N side)
#define COLS_PER_CHUNK 2048    // Y rows streamed per block
#define TILES (COLS_PER_CHUNK / BM)           // 16
#define KSTEPS 4               // 512 / 128 (BK = 128 int8 per step)
#define NSEG 8                 // Y segments (s>>3)
#define NZ 4                   // Y sub-segments (grid.z)
#define LPT 8                  // per-lane top-K (i8 coarse noise needs 8)
#define KEEP 8                 // kept per (row, slot)
#define NCAND (NSEG * NZ * KEEP)              // 256 per row
#define RESC 16                // rescored per row (29-sigma margin)
#define QS 24.f                // int8 quantization scale

typedef int i32x4 __attribute__((ext_vector_type(4)));

#define AS1(p) (const __attribute__((address_space(1))) void*)(p)
#define AS3(p) (__attribute__((address_space(3))) void*)(p)

__device__ __forceinline__ int q24(float x) {
    float r = rintf(x * QS);
    r = fminf(127.f, fmaxf(-127.f, r));
    return (int)r;
}

__device__ __forceinline__ unsigned int umin_(unsigned int a, unsigned int b) { return a < b ? a : b; }

// branchless sorted-insert (ascending): 1 min + (K-1) med3, no divergence.
template <int K>
__device__ __forceinline__ void pushk_b(unsigned int x, unsigned int (&l)[K]) {
    unsigned int prev = l[0];
    l[0] = umin_(l[0], x);
#pragma unroll
    for (int i = 1; i < K; ++i) {
        unsigned int cur = l[i];
        unsigned int m;
        asm("v_med3_u32 %0, %1, %2, %3" : "=v"(m) : "v"(x), "v"(prev), "v"(cur));
        l[i] = m;
        prev = cur;
    }
}

// branchy insert (serial contexts: cheap reject dominates)
template <int K>
__device__ __forceinline__ void pushk(unsigned int k, unsigned int (&lst)[K]) {
    if (k >= lst[K - 1]) return;
    lst[K - 1] = k;
#pragma unroll
    for (int p = K - 1; p > 0; --p) {
        if (lst[p] < lst[p - 1]) {
            unsigned int t = lst[p]; lst[p] = lst[p - 1]; lst[p - 1] = t;
        }
    }
}

template <int K>
__device__ __forceinline__ void push(float d, int gi, float (&bd)[K], int (&bi)[K]) {
    if (d > bd[K - 1] || (d == bd[K - 1] && gi >= bi[K - 1])) return;
    bd[K - 1] = d; bi[K - 1] = gi;
#pragma unroll
    for (int p = K - 1; p > 0; --p) {
        bool sw = (bd[p] < bd[p - 1]) || (bd[p] == bd[p - 1] && bi[p] < bi[p - 1]);
        if (sw) {
            float td = bd[p]; bd[p] = bd[p - 1]; bd[p - 1] = td;
            int   ti = bi[p]; bi[p] = bi[p - 1]; bi[p - 1] = ti;
        }
    }
}

// X: quantize 8 elems/thread to int8
__global__ void cvt_q_x(const float* __restrict__ src, signed char* __restrict__ dst, int n8) {
    int i = blockIdx.x * blockDim.x + threadIdx.x;
    if (i >= n8) return;
    const float4* s = (const float4*)src;
    float4 a0 = s[i * 2], a1 = s[i * 2 + 1];
    int lo = (q24(a0.x) & 255) | ((q24(a0.y) & 255) << 8)
           | ((q24(a0.z) & 255) << 16) | ((q24(a0.w) & 255) << 24);
    int hi = (q24(a1.x) & 255) | ((q24(a1.y) & 255) << 8)
           | ((q24(a1.z) & 255) << 16) | ((q24(a1.w) & 255) << 24);
    int2 v; v.x = lo; v.y = hi;
    *(int2*)(dst + (size_t)i * 8) = v;
}

// Fused per Y row: fp64 ysq (EXACT round-1 summation order, bit-identical) +
// int8 quantize + exact integer ||y_q||^2. One wave per row.
__global__ void ysq_cvt_q(const float* __restrict__ Y, float* __restrict__ ysq,
                          int* __restrict__ ysqq, signed char* __restrict__ Yq) {
    int row  = (blockIdx.x * blockDim.x + threadIdx.x) >> 6;
    int lane = threadIdx.x & 63;
    if (row >= NY) return;
    const float4* yr = reinterpret_cast<const float4*>(Y + (size_t)row * DIM);
    signed char* dst = Yq + (size_t)row * DIM;
    double s = 0.0;
    int sq = 0;
#pragma unroll
    for (int i = 0; i < 2; ++i) {
        float4 v = yr[lane + 64 * i];
        s += (double)v.x * v.x + (double)v.y * v.y + (double)v.z * v.z + (double)v.w * v.w;
        int q0 = q24(v.x), q1 = q24(v.y), q2 = q24(v.z), q3 = q24(v.w);
        sq += q0 * q0 + q1 * q1 + q2 * q2 + q3 * q3;
        int packed = (q0 & 255) | ((q1 & 255) << 8) | ((q2 & 255) << 16) | ((q3 & 255) << 24);
        *(int*)(dst + i * 256 + lane * 4) = packed;
    }
#pragma unroll
    for (int off = 32; off > 0; off >>= 1) {
        s  += __shfl_xor(s, off, 64);
        sq += __shfl_xor(sq, off, 64);
    }
    if (lane == 0) { ysq[row] = (float)s; ysqq[row] = sq; }
}

// Coarse: int8 MFMA (16x16x64), r15 schedule byte-identical (128-B LDS rows,
// same swizzle, same fragment offsets), 4 K-steps/tile, integer keys.
__global__ __launch_bounds__(256, 2) void knn_coarse_fast(
        const signed char* __restrict__ Xq, const signed char* __restrict__ Yq,
        const int* __restrict__ ysqq,
        unsigned int* __restrict__ cand_k) {
    __shared__ __align__(16) char smem[65536];
    char* As = smem;
    char* Bs = smem + 32768;

    const int tid  = threadIdx.x;
    const int lane = tid & 63;
    const int w    = tid >> 6;
    const int l15  = lane & 15;
    const int lg   = lane >> 4;              // 0..3
    const int xcd  = blockIdx.x;             // 0..7 (linear%8 == blockIdx.x)
    const int s_   = blockIdx.y;             // 0..63
    const int z    = blockIdx.z;             // 0..3
    const int row0  = (xcd * 8 + (s_ & 7)) * BN;   // X tile (8 per XCD resident)
    const int yseg  = s_ >> 3;               // 0..7
    const int ybase = yseg * (NY / NSEG) + z * COLS_PER_CHUNK;
    const int slot  = yseg * NZ + z;         // 0..31 candidate slot
    const int m0 = (w >> 1) * 64;            // wave quadrant: Y side
    const int n0 = (w & 1) * 64;             //                X side

    const int srow = lane >> 3;                     // 0..7
    const int scb  = ((lane & 7) ^ srow) << 4;      // swizzled source chunk
    const char* pXbase = (const char*)Xq
        + ((size_t)(row0 + w * 32 + srow) << 9) + scb;

#define STAGE(tt, kcc, buf)                                                      \
    {                                                                            \
        const char* pY_ = (const char*)Yq                                        \
            + ((size_t)(ybase + (tt) * BM + w * 32 + srow) << 9)                 \
            + ((kcc) << 7) + scb;                                                \
        const char* pX_ = pXbase + ((kcc) << 7);                                 \
        char* dA_ = As + ((buf) << 14) + (w << 12);                              \
        char* dB_ = Bs + ((buf) << 14) + (w << 12);                              \
        _Pragma("unroll")                                                        \
        for (int q = 0; q < 4; ++q) {                                            \
            __builtin_amdgcn_global_load_lds(AS1(pY_ + ((size_t)(q * 8) << 9)),  \
                                             AS3(dA_ + (q << 10)), 16, 0, 0);    \
            __builtin_amdgcn_global_load_lds(AS1(pX_ + ((size_t)(q * 8) << 9)),  \
                                             AS3(dB_ + (q << 10)), 16, 0, 0);    \
        }                                                                        \
    }

    unsigned int kb_[4][LPT];
#pragma unroll
    for (int nf = 0; nf < 4; ++nf)
#pragma unroll
        for (int m = 0; m < LPT; ++m) kb_[nf][m] = 0xffffffffu;

    STAGE(0, 0, 0);   // prologue: 8 loads in flight

    for (int t = 0; t < TILES; ++t) {
        const int ytile0 = ybase + t * BM;

        // ysq_q rows this lane needs (asm: FIFO-tracked; drained by kc=1 vmcnt(0))
        i32x4 yv0, yv1, yv2, yv3;
        {
            const int* yp = ysqq + ytile0 + m0 + lg * 4;
            asm volatile("global_load_dwordx4 %0, %1, off" : "=v"(yv0) : "v"(yp));
            asm volatile("global_load_dwordx4 %0, %1, off" : "=v"(yv1) : "v"(yp + 16));
            asm volatile("global_load_dwordx4 %0, %1, off" : "=v"(yv2) : "v"(yp + 32));
            asm volatile("global_load_dwordx4 %0, %1, off" : "=v"(yv3) : "v"(yp + 48));
        }

        i32x4 acc[4][4];
#pragma unroll
        for (int i = 0; i < 4; ++i)
#pragma unroll
            for (int j = 0; j < 4; ++j) acc[i][j] = (i32x4){0, 0, 0, 0};

#pragma unroll
        for (int kc = 0; kc < KSTEPS; ++kc) {
            const int buf = kc & 1;
            if (kc == 0) asm volatile("s_waitcnt vmcnt(4)" ::: "memory");
            else         asm volatile("s_waitcnt vmcnt(0)" ::: "memory");
            __builtin_amdgcn_sched_barrier(0);
            __builtin_amdgcn_s_barrier();
            if (kc < KSTEPS - 1) {
                STAGE(t, kc + 1, buf ^ 1);
            } else if (t + 1 < TILES) {
                STAGE(t + 1, 0, buf ^ 1);
            }

            const char* Ab = As + (buf << 14);
            const char* Bb = Bs + (buf << 14);
#pragma unroll
            for (int kk = 0; kk < 2; ++kk) {
                const int kbyte = kk * 64 + lg * 16;
                const int sw = kbyte ^ ((l15 & 7) << 4);
                i32x4 af[4], bf[4];
#pragma unroll
                for (int mf = 0; mf < 4; ++mf)
                    af[mf] = *(const i32x4*)(Ab + ((m0 + mf * 16 + l15) << 7) + sw);
#pragma unroll
                for (int nf = 0; nf < 4; ++nf)
                    bf[nf] = *(const i32x4*)(Bb + ((n0 + nf * 16 + l15) << 7) + sw);
                __builtin_amdgcn_s_setprio(1);
#pragma unroll
                for (int mf = 0; mf < 4; ++mf)
#pragma unroll
                    for (int nf = 0; nf < 4; ++nf)
                        acc[mf][nf] = __builtin_amdgcn_mfma_i32_16x16x64_i8(
                            af[mf], bf[nf], acc[mf][nf], 0, 0, 0);
                __builtin_amdgcn_s_setprio(0);
            }
        }

        // epilogue: d_q = ysq_q - 2*dot (exact i32); key = (min(d_q>>6,65535)<<16)|yi
#pragma unroll
        for (int mf = 0; mf < 4; ++mf) {
            const int gib = ytile0 + m0 + mf * 16 + lg * 4;
            const i32x4 yv = (mf == 0) ? yv0 : (mf == 1) ? yv1 : (mf == 2) ? yv2 : yv3;
#pragma unroll
            for (int nf = 0; nf < 4; ++nf) {
#pragma unroll
                for (int j = 0; j < 4; ++j) {
                    int dq = yv[j] - 2 * acc[mf][nf][j];
                    unsigned int ud = (unsigned int)(dq > 0 ? dq : 0);
                    unsigned int key = (umin_(ud >> 6, 65535u) << 16)
                                     | (unsigned int)(gib + j);
                    pushk_b<LPT>(key, kb_[nf]);
                }
            }
        }
    }
#undef STAGE

    // ---- merge 8 lane-lists per X row (reuses smem; r11-proven layout) ----
    __syncthreads();
    unsigned int* mbuf = (unsigned int*)smem;   // 128 rows x 66 dwords = 33.8 KB
    const int mslot = (w >> 1) * 4 + lg;        // 0..7
#pragma unroll
    for (int nf = 0; nf < 4; ++nf) {
        const int r = n0 + nf * 16 + l15;
#pragma unroll
        for (int e = 0; e < LPT; ++e)
            mbuf[r * 66 + mslot * LPT + e] = kb_[nf][e];
    }
    __syncthreads();
    if (tid < 128) {
        unsigned int mk[KEEP];
#pragma unroll
        for (int m = 0; m < KEEP; ++m) mk[m] = 0xffffffffu;
        for (int s2 = 0; s2 < 8; ++s2)
#pragma unroll
            for (int e = 0; e < LPT; ++e)
                pushk_b<KEEP>(mbuf[tid * 66 + s2 * LPT + e], mk);
        const int row = row0 + tid;
        unsigned int* co = cand_k + (size_t)row * NCAND + slot * KEEP;
#pragma unroll
        for (int m = 0; m < KEEP; ++m) co[m] = mk[m];
    }
}

// Rescore: coarse top-16 of 256 packed keys, then BIT-EXACT round-1 arithmetic.
// 16 rows per block.
__global__ __launch_bounds__(256) void knn_rescore(
        const float* __restrict__ X, const float* __restrict__ Y,
        const float* __restrict__ ysq,
        const unsigned int* __restrict__ cand_k,
        int* __restrict__ out) {
    __shared__ unsigned int ck[16][NCAND];
    __shared__ int   rci[16][RESC];
    __shared__ float rd[16][RESC];

    const int tid  = threadIdx.x;
    const int row0 = blockIdx.x * 16;

#pragma unroll
    for (int q = 0; q < 16; ++q) {
        const int idx = q * 256 + tid;       // 0..4095
        const int r = idx >> 8, j = idx & 255;
        ck[r][j] = cand_k[(size_t)(row0 + r) * NCAND + j];
    }
    __syncthreads();

    if (tid < 16) {
        unsigned int mk[RESC];
#pragma unroll
        for (int m = 0; m < RESC; ++m) mk[m] = 0xffffffffu;
        for (int j = 0; j < NCAND; ++j) pushk<RESC>(ck[tid][j], mk);
#pragma unroll
        for (int m = 0; m < RESC; ++m) rci[tid][m] = (int)(mk[m] & 0xffffu);
    }
    __syncthreads();

    {
        const int r = tid >> 4, c = tid & 15;
        const int row = row0 + r;
        const int yi = rci[r][c];
        const float* xr = X + (size_t)row * DIM;
        const float* yr = Y + (size_t)yi * DIM;
        double acc64 = 0.0;
        for (int kc = 0; kc < DIM; kc += 64) {
            float acc = 0.f;
#pragma unroll
            for (int k4 = 0; k4 < 16; ++k4) {
                float4 xv = *(const float4*)(xr + kc + k4 * 4);
                float4 yv = *(const float4*)(yr + kc + k4 * 4);
                acc = fmaf(xv.x, yv.x, acc);
                acc = fmaf(xv.y, yv.y, acc);
                acc = fmaf(xv.z, yv.z, acc);
                acc = fmaf(xv.w, yv.w, acc);
            }
            acc64 += (double)acc;
        }
        rd[r][c] = (float)((double)ysq[yi] - 2.0 * acc64);
    }
    __syncthreads();

    if (tid < 16) {
        float fd[KNN]; int fi[KNN];
#pragma unroll
        for (int m = 0; m < KNN; ++m) { fd[m] = INFINITY; fi[m] = 0x7fffffff; }
        for (int j = 0; j < RESC; ++j) push<KNN>(rd[tid][j], rci[tid][j], fd, fi);
        const int row = row0 + tid;
#pragma unroll
        for (int m = 0; m < KNN; ++m) out[row * KNN + m] = fi[m];
    }
}

extern "C" void kernel_launch(void* const* d_in, const int* in_sizes, int n_in,
                              void* d_out, int out_size, void* d_ws, size_t ws_size,
                              hipStream_t stream) {
    const float* X = (const float*)d_in[0];   // [8192, 512]
    const float* Y = (const float*)d_in[1];   // [65536, 512]
    int* out = (int*)d_out;                   // [8192, 8] int32

    char* ws = (char*)d_ws;
    float* ysq           = (float*)ws;                              // 256 KB
    int*   ysqq          = (int*)(ws + 262144);                     // 256 KB
    unsigned int* cand_k = (unsigned int*)(ws + 524288);            // 8 MB
    signed char* Xq      = (signed char*)(ws + 524288 + (size_t)NX * NCAND * 4);  // 4 MB
    signed char* Yq      = Xq + (size_t)NX * DIM;                   // 32 MB

    ysq_cvt_q<<<NY / 4, 256, 0, stream>>>(Y, ysq, ysqq, Yq);
    cvt_q_x<<<(NX * DIM / 8) / 256, 256, 0, stream>>>(X, Xq, NX * DIM / 8);

    dim3 g1(8, 64, NZ);   // 2048 blocks; linear%8 = blockIdx.x = xcd
    knn_coarse_fast<<<g1, 256, 0, stream>>>(Xq, Yq, ysqq, cand_k);

    knn_rescore<<<NX / 16, 256, 0, stream>>>(X, Y, ysq, cand_k, out);
}

// Round 17
// 516.991 us; speedup vs baseline: 2.0896x; 1.0384x over previous
//
#include <hip/hip_runtime.h>
#include <math.h>

#define NX 8192
#define NY 65536
#define DIM 512
#define KNN 8

#define BM 128                 // Y rows per tile (MFMA M side)
#define BN 64                  // X rows per block (MFMA N side)
#define COLS_PER_CHUNK 2048    // Y rows streamed per block
#define TILES (COLS_PER_CHUNK / BM)           // 16
#define KSTEPS 4               // 512 / 128 (BK = 128 int8 per step)
#define NSEG 8                 // Y segments (s>>4)
#define NZ 4                   // Y sub-segments (grid.z)
#define LPT 8                  // per-lane top-K (i8 coarse noise needs 8)
#define KEEP 8                 // kept per (row, slot)
#define NCAND (NSEG * NZ * KEEP)              // 256 per row
#define RESC 16                // rescored per row
#define QS 24.f                // int8 quantization scale
#define DBIAS (1 << 19)        // key bias: dq in [-380k, 500k] -> always >= 0

typedef int i32x4 __attribute__((ext_vector_type(4)));

#define AS1(p) (const __attribute__((address_space(1))) void*)(p)
#define AS3(p) (__attribute__((address_space(3))) void*)(p)

__device__ __forceinline__ int q24(float x) {
    float r = rintf(x * QS);
    r = fminf(127.f, fmaxf(-127.f, r));
    return (int)r;
}

__device__ __forceinline__ unsigned int umin_(unsigned int a, unsigned int b) { return a < b ? a : b; }

// branchless sorted-insert (ascending): 1 min + (K-1) med3, no divergence.
template <int K>
__device__ __forceinline__ void pushk_b(unsigned int x, unsigned int (&l)[K]) {
    unsigned int prev = l[0];
    l[0] = umin_(l[0], x);
#pragma unroll
    for (int i = 1; i < K; ++i) {
        unsigned int cur = l[i];
        unsigned int m;
        asm("v_med3_u32 %0, %1, %2, %3" : "=v"(m) : "v"(x), "v"(prev), "v"(cur));
        l[i] = m;
        prev = cur;
    }
}

// branchy insert (serial contexts: cheap reject dominates)
template <int K>
__device__ __forceinline__ void pushk(unsigned int k, unsigned int (&lst)[K]) {
    if (k >= lst[K - 1]) return;
    lst[K - 1] = k;
#pragma unroll
    for (int p = K - 1; p > 0; --p) {
        if (lst[p] < lst[p - 1]) {
            unsigned int t = lst[p]; lst[p] = lst[p - 1]; lst[p - 1] = t;
        }
    }
}

template <int K>
__device__ __forceinline__ void push(float d, int gi, float (&bd)[K], int (&bi)[K]) {
    if (d > bd[K - 1] || (d == bd[K - 1] && gi >= bi[K - 1])) return;
    bd[K - 1] = d; bi[K - 1] = gi;
#pragma unroll
    for (int p = K - 1; p > 0; --p) {
        bool sw = (bd[p] < bd[p - 1]) || (bd[p] == bd[p - 1] && bi[p] < bi[p - 1]);
        if (sw) {
            float td = bd[p]; bd[p] = bd[p - 1]; bd[p - 1] = td;
            int   ti = bi[p]; bi[p] = bi[p - 1]; bi[p - 1] = ti;
        }
    }
}

// X: quantize 8 elems/thread to int8
__global__ void cvt_q_x(const float* __restrict__ src, signed char* __restrict__ dst, int n8) {
    int i = blockIdx.x * blockDim.x + threadIdx.x;
    if (i >= n8) return;
    const float4* s = (const float4*)src;
    float4 a0 = s[i * 2], a1 = s[i * 2 + 1];
    int lo = (q24(a0.x) & 255) | ((q24(a0.y) & 255) << 8)
           | ((q24(a0.z) & 255) << 16) | ((q24(a0.w) & 255) << 24);
    int hi = (q24(a1.x) & 255) | ((q24(a1.y) & 255) << 8)
           | ((q24(a1.z) & 255) << 16) | ((q24(a1.w) & 255) << 24);
    int2 v; v.x = lo; v.y = hi;
    *(int2*)(dst + (size_t)i * 8) = v;
}

// Fused per Y row: fp64 ysq (EXACT round-1 summation order, bit-identical) +
// int8 quantize + exact integer ||y_q||^2 (+DBIAS for key arithmetic).
__global__ void ysq_cvt_q(const float* __restrict__ Y, float* __restrict__ ysq,
                          int* __restrict__ ysqq, signed char* __restrict__ Yq) {
    int row  = (blockIdx.x * blockDim.x + threadIdx.x) >> 6;
    int lane = threadIdx.x & 63;
    if (row >= NY) return;
    const float4* yr = reinterpret_cast<const float4*>(Y + (size_t)row * DIM);
    signed char* dst = Yq + (size_t)row * DIM;
    double s = 0.0;
    int sq = 0;
#pragma unroll
    for (int i = 0; i < 2; ++i) {
        float4 v = yr[lane + 64 * i];
        s += (double)v.x * v.x + (double)v.y * v.y + (double)v.z * v.z + (double)v.w * v.w;
        int q0 = q24(v.x), q1 = q24(v.y), q2 = q24(v.z), q3 = q24(v.w);
        sq += q0 * q0 + q1 * q1 + q2 * q2 + q3 * q3;
        int packed = (q0 & 255) | ((q1 & 255) << 8) | ((q2 & 255) << 16) | ((q3 & 255) << 24);
        *(int*)(dst + i * 256 + lane * 4) = packed;
    }
#pragma unroll
    for (int off = 32; off > 0; off >>= 1) {
        s  += __shfl_xor(s, off, 64);
        sq += __shfl_xor(sq, off, 64);
    }
    if (lane == 0) { ysq[row] = (float)s; ysqq[row] = sq + DBIAS; }
}

// Coarse: int8 MFMA (16x16x64), 128x64 block (As dbuf 32K + Bs dbuf 16K =
// 48 KB -> 3 blocks/CU), r16 schedule otherwise identical; 3-op keys.
__global__ __launch_bounds__(256, 3) void knn_coarse_fast(
        const signed char* __restrict__ Xq, const signed char* __restrict__ Yq,
        const int* __restrict__ ysqq,
        unsigned int* __restrict__ cand_k) {
    __shared__ __align__(16) char smem[49152];
    char* As = smem;           // 2 x [128 rows][128 B]
    char* Bs = smem + 32768;   // 2 x [64 rows][128 B]

    const int tid  = threadIdx.x;
    const int lane = tid & 63;
    const int w    = tid >> 6;
    const int l15  = lane & 15;
    const int lg   = lane >> 4;              // 0..3
    const int xcd  = blockIdx.x;             // 0..7 (linear%8 == blockIdx.x)
    const int s_   = blockIdx.y;             // 0..127
    const int z    = blockIdx.z;             // 0..3
    const int row0  = (xcd * 16 + (s_ & 15)) * BN;  // X tile (16/XCD = 512 KB)
    const int yseg  = s_ >> 4;               // 0..7
    const int ybase = yseg * (NY / NSEG) + z * COLS_PER_CHUNK;
    const int slot  = yseg * NZ + z;         // 0..31 candidate slot
    const int m0 = (w >> 1) * 64;            // wave quadrant: Y side (2-way)
    const int n0 = (w & 1) * 32;             //                X side (2-way)

    const int srow = lane >> 3;                     // 0..7
    const int scb  = ((lane & 7) ^ srow) << 4;      // swizzled source chunk
    const char* pXbase = (const char*)Xq
        + ((size_t)(row0 + w * 16 + srow) << 9) + scb;

#define STAGE(tt, kcc, buf)                                                      \
    {                                                                            \
        const char* pY_ = (const char*)Yq                                        \
            + ((size_t)(ybase + (tt) * BM + w * 32 + srow) << 9)                 \
            + ((kcc) << 7) + scb;                                                \
        const char* pX_ = pXbase + ((kcc) << 7);                                 \
        char* dA_ = As + ((buf) << 14) + (w << 12);                              \
        char* dB_ = Bs + ((buf) << 13) + (w << 11);                              \
        _Pragma("unroll")                                                        \
        for (int q = 0; q < 4; ++q)                                              \
            __builtin_amdgcn_global_load_lds(AS1(pY_ + ((size_t)(q * 8) << 9)),  \
                                             AS3(dA_ + (q << 10)), 16, 0, 0);    \
        _Pragma("unroll")                                                        \
        for (int q = 0; q < 2; ++q)                                              \
            __builtin_amdgcn_global_load_lds(AS1(pX_ + ((size_t)(q * 8) << 9)),  \
                                             AS3(dB_ + (q << 10)), 16, 0, 0);    \
    }

    unsigned int kb_[2][LPT];
#pragma unroll
    for (int nf = 0; nf < 2; ++nf)
#pragma unroll
        for (int m = 0; m < LPT; ++m) kb_[nf][m] = 0xffffffffu;

    STAGE(0, 0, 0);   // prologue: 6 loads in flight

    for (int t = 0; t < TILES; ++t) {
        const int ytile0 = ybase + t * BM;

        // biased ysq_q rows (asm: FIFO-tracked; drained by kc=1 vmcnt(0))
        i32x4 yv0, yv1, yv2, yv3;
        {
            const int* yp = ysqq + ytile0 + m0 + lg * 4;
            asm volatile("global_load_dwordx4 %0, %1, off" : "=v"(yv0) : "v"(yp));
            asm volatile("global_load_dwordx4 %0, %1, off" : "=v"(yv1) : "v"(yp + 16));
            asm volatile("global_load_dwordx4 %0, %1, off" : "=v"(yv2) : "v"(yp + 32));
            asm volatile("global_load_dwordx4 %0, %1, off" : "=v"(yv3) : "v"(yp + 48));
        }

        i32x4 acc[4][2];
#pragma unroll
        for (int i = 0; i < 4; ++i)
#pragma unroll
            for (int j = 0; j < 2; ++j) acc[i][j] = (i32x4){0, 0, 0, 0};

#pragma unroll
        for (int kc = 0; kc < KSTEPS; ++kc) {
            const int buf = kc & 1;
            if (kc == 0) asm volatile("s_waitcnt vmcnt(4)" ::: "memory");
            else         asm volatile("s_waitcnt vmcnt(0)" ::: "memory");
            __builtin_amdgcn_sched_barrier(0);
            __builtin_amdgcn_s_barrier();
            if (kc < KSTEPS - 1) {
                STAGE(t, kc + 1, buf ^ 1);
            } else if (t + 1 < TILES) {
                STAGE(t + 1, 0, buf ^ 1);
            }

            const char* Ab = As + (buf << 14);
            const char* Bb = Bs + (buf << 13);
#pragma unroll
            for (int kk = 0; kk < 2; ++kk) {
                const int kbyte = kk * 64 + lg * 16;
                const int sw = kbyte ^ ((l15 & 7) << 4);
                i32x4 af[4], bf[2];
#pragma unroll
                for (int mf = 0; mf < 4; ++mf)
                    af[mf] = *(const i32x4*)(Ab + ((m0 + mf * 16 + l15) << 7) + sw);
#pragma unroll
                for (int nf = 0; nf < 2; ++nf)
                    bf[nf] = *(const i32x4*)(Bb + ((n0 + nf * 16 + l15) << 7) + sw);
                __builtin_amdgcn_s_setprio(1);
#pragma unroll
                for (int mf = 0; mf < 4; ++mf)
#pragma unroll
                    for (int nf = 0; nf < 2; ++nf)
                        acc[mf][nf] = __builtin_amdgcn_mfma_i32_16x16x64_i8(
                            af[mf], bf[nf], acc[mf][nf], 0, 0, 0);
                __builtin_amdgcn_s_setprio(0);
            }
        }

        // epilogue: dq_b = yvb - 2*dot (i24-mad, exact, always >=0 via DBIAS);
        // key = ((dq_b << 10) & 0xFFFF0000) | gi   (3 VALU ops/cand)
#pragma unroll
        for (int mf = 0; mf < 4; ++mf) {
            const int gib = ytile0 + m0 + mf * 16 + lg * 4;
            const i32x4 yv = (mf == 0) ? yv0 : (mf == 1) ? yv1 : (mf == 2) ? yv2 : yv3;
            int gi[4];
#pragma unroll
            for (int j = 0; j < 4; ++j) gi[j] = gib + j;
#pragma unroll
            for (int nf = 0; nf < 2; ++nf) {
#pragma unroll
                for (int j = 0; j < 4; ++j) {
                    int dqb;
                    asm("v_mad_i32_i24 %0, %1, -2, %2"
                        : "=v"(dqb) : "v"(acc[mf][nf][j]), "v"(yv[j]));
                    unsigned int key = (((unsigned int)dqb << 10) & 0xFFFF0000u)
                                     | (unsigned int)gi[j];
                    pushk_b<LPT>(key, kb_[nf]);
                }
            }
        }
    }
#undef STAGE

    // ---- merge 8 lane-lists per X row (reuses smem) ----
    __syncthreads();
    unsigned int* mbuf = (unsigned int*)smem;   // 64 rows x 66 dwords = 16.9 KB
    const int mslot = (w >> 1) * 4 + lg;        // 0..7
#pragma unroll
    for (int nf = 0; nf < 2; ++nf) {
        const int r = n0 + nf * 16 + l15;       // 0..63
#pragma unroll
        for (int e = 0; e < LPT; ++e)
            mbuf[r * 66 + mslot * LPT + e] = kb_[nf][e];
    }
    __syncthreads();
    if (tid < 64) {
        unsigned int mk[KEEP];
#pragma unroll
        for (int m = 0; m < KEEP; ++m) mk[m] = 0xffffffffu;
        for (int s2 = 0; s2 < 8; ++s2)
#pragma unroll
            for (int e = 0; e < LPT; ++e)
                pushk_b<KEEP>(mbuf[tid * 66 + s2 * LPT + e], mk);
        const int row = row0 + tid;
        unsigned int* co = cand_k + (size_t)row * NCAND + slot * KEEP;
#pragma unroll
        for (int m = 0; m < KEEP; ++m) co[m] = mk[m];
    }
}

// Rescore: coarse top-16 of 256 packed keys, then BIT-EXACT round-1 arithmetic.
__global__ __launch_bounds__(256) void knn_rescore(
        const float* __restrict__ X, const float* __restrict__ Y,
        const float* __restrict__ ysq,
        const unsigned int* __restrict__ cand_k,
        int* __restrict__ out) {
    __shared__ unsigned int ck[16][NCAND];
    __shared__ int   rci[16][RESC];
    __shared__ float rd[16][RESC];

    const int tid  = threadIdx.x;
    const int row0 = blockIdx.x * 16;

#pragma unroll
    for (int q = 0; q < 16; ++q) {
        const int idx = q * 256 + tid;       // 0..4095
        const int r = idx >> 8, j = idx & 255;
        ck[r][j] = cand_k[(size_t)(row0 + r) * NCAND + j];
    }
    __syncthreads();

    if (tid < 16) {
        unsigned int mk[RESC];
#pragma unroll
        for (int m = 0; m < RESC; ++m) mk[m] = 0xffffffffu;
        for (int j = 0; j < NCAND; ++j) pushk<RESC>(ck[tid][j], mk);
#pragma unroll
        for (int m = 0; m < RESC; ++m) rci[tid][m] = (int)(mk[m] & 0xffffu);
    }
    __syncthreads();

    {
        const int r = tid >> 4, c = tid & 15;
        const int row = row0 + r;
        const int yi = rci[r][c];
        const float* xr = X + (size_t)row * DIM;
        const float* yr = Y + (size_t)yi * DIM;
        double acc64 = 0.0;
        for (int kc = 0; kc < DIM; kc += 64) {
            float acc = 0.f;
#pragma unroll
            for (int k4 = 0; k4 < 16; ++k4) {
                float4 xv = *(const float4*)(xr + kc + k4 * 4);
                float4 yv = *(const float4*)(yr + kc + k4 * 4);
                acc = fmaf(xv.x, yv.x, acc);
                acc = fmaf(xv.y, yv.y, acc);
                acc = fmaf(xv.z, yv.z, acc);
                acc = fmaf(xv.w, yv.w, acc);
            }
            acc64 += (double)acc;
        }
        rd[r][c] = (float)((double)ysq[yi] - 2.0 * acc64);
    }
    __syncthreads();

    if (tid < 16) {
        float fd[KNN]; int fi[KNN];
#pragma unroll
        for (int m = 0; m < KNN; ++m) { fd[m] = INFINITY; fi[m] = 0x7fffffff; }
        for (int j = 0; j < RESC; ++j) push<KNN>(rd[tid][j], rci[tid][j], fd, fi);
        const int row = row0 + tid;
#pragma unroll
        for (int m = 0; m < KNN; ++m) out[row * KNN + m] = fi[m];
    }
}

extern "C" void kernel_launch(void* const* d_in, const int* in_sizes, int n_in,
                              void* d_out, int out_size, void* d_ws, size_t ws_size,
                              hipStream_t stream) {
    const float* X = (const float*)d_in[0];   // [8192, 512]
    const float* Y = (const float*)d_in[1];   // [65536, 512]
    int* out = (int*)d_out;                   // [8192, 8] int32

    char* ws = (char*)d_ws;
    float* ysq           = (float*)ws;                              // 256 KB
    int*   ysqq          = (int*)(ws + 262144);                     // 256 KB
    unsigned int* cand_k = (unsigned int*)(ws + 524288);            // 8 MB
    signed char* Xq      = (signed char*)(ws + 524288 + (size_t)NX * NCAND * 4);  // 4 MB
    signed char* Yq      = Xq + (size_t)NX * DIM;                   // 32 MB

    ysq_cvt_q<<<NY / 4, 256, 0, stream>>>(Y, ysq, ysqq, Yq);
    cvt_q_x<<<(NX * DIM / 8) / 256, 256, 0, stream>>>(X, Xq, NX * DIM / 8);

    dim3 g1(8, 128, NZ);   // 4096 blocks; linear%8 = blockIdx.x = xcd
    knn_coarse_fast<<<g1, 256, 0, stream>>>(Xq, Yq, ysqq, cand_k);

    knn_rescore<<<NX / 16, 256, 0, stream>>>(X, Y, ysq, cand_k, out);
}

// Round 18
// 468.547 us; speedup vs baseline: 2.3057x; 1.1034x over previous
//
#include <hip/hip_runtime.h>
#include <math.h>

#define NX 8192
#define NY 65536
#define DIM 512
#define KNN 8

#define BM 128                 // Y rows per tile (MFMA M side)
#define BN 128                 // X rows per block (MFMA N side)
#define COLS_PER_CHUNK 2048    // Y rows streamed per block
#define TILES (COLS_PER_CHUNK / BM)           // 16
#define KSTEPS 4               // 512 / 128 (BK = 128 int8 per step)
#define NSEG 8                 // Y segments (s>>3)
#define NZ 4                   // Y sub-segments (grid.z)
#define LPT 8                  // per-lane chunk-level top-K
#define KEEP 8                 // kept per (row, slot)
#define NCAND (NSEG * NZ * KEEP)              // 256 per row
#define RESC 16                // rescored per row
#define QS 24.f                // int8 quantization scale
#define DBIAS (1 << 19)        // key bias: dq always >= 0 after bias

typedef int i32x4 __attribute__((ext_vector_type(4)));

#define AS1(p) (const __attribute__((address_space(1))) void*)(p)
#define AS3(p) (__attribute__((address_space(3))) void*)(p)

__device__ __forceinline__ int q24(float x) {
    float r = rintf(x * QS);
    r = fminf(127.f, fmaxf(-127.f, r));
    return (int)r;
}

__device__ __forceinline__ unsigned int umin_(unsigned int a, unsigned int b) { return a < b ? a : b; }

// branchless sorted-insert (ascending): 1 min + (K-1) med3, no divergence.
template <int K>
__device__ __forceinline__ void pushk_b(unsigned int x, unsigned int (&l)[K]) {
    unsigned int prev = l[0];
    l[0] = umin_(l[0], x);
#pragma unroll
    for (int i = 1; i < K; ++i) {
        unsigned int cur = l[i];
        unsigned int m;
        asm("v_med3_u32 %0, %1, %2, %3" : "=v"(m) : "v"(x), "v"(prev), "v"(cur));
        l[i] = m;
        prev = cur;
    }
}

// branchy insert (serial contexts: cheap reject dominates)
template <int K>
__device__ __forceinline__ void pushk(unsigned int k, unsigned int (&lst)[K]) {
    if (k >= lst[K - 1]) return;
    lst[K - 1] = k;
#pragma unroll
    for (int p = K - 1; p > 0; --p) {
        if (lst[p] < lst[p - 1]) {
            unsigned int t = lst[p]; lst[p] = lst[p - 1]; lst[p - 1] = t;
        }
    }
}

template <int K>
__device__ __forceinline__ void push(float d, int gi, float (&bd)[K], int (&bi)[K]) {
    if (d > bd[K - 1] || (d == bd[K - 1] && gi >= bi[K - 1])) return;
    bd[K - 1] = d; bi[K - 1] = gi;
#pragma unroll
    for (int p = K - 1; p > 0; --p) {
        bool sw = (bd[p] < bd[p - 1]) || (bd[p] == bd[p - 1] && bi[p] < bi[p - 1]);
        if (sw) {
            float td = bd[p]; bd[p] = bd[p - 1]; bd[p - 1] = td;
            int   ti = bi[p]; bi[p] = bi[p - 1]; bi[p - 1] = ti;
        }
    }
}

// X: quantize 8 elems/thread to int8
__global__ void cvt_q_x(const float* __restrict__ src, signed char* __restrict__ dst, int n8) {
    int i = blockIdx.x * blockDim.x + threadIdx.x;
    if (i >= n8) return;
    const float4* s = (const float4*)src;
    float4 a0 = s[i * 2], a1 = s[i * 2 + 1];
    int lo = (q24(a0.x) & 255) | ((q24(a0.y) & 255) << 8)
           | ((q24(a0.z) & 255) << 16) | ((q24(a0.w) & 255) << 24);
    int hi = (q24(a1.x) & 255) | ((q24(a1.y) & 255) << 8)
           | ((q24(a1.z) & 255) << 16) | ((q24(a1.w) & 255) << 24);
    int2 v; v.x = lo; v.y = hi;
    *(int2*)(dst + (size_t)i * 8) = v;
}

// Fused per Y row: fp64 ysq (EXACT round-1 summation order, bit-identical) +
// int8 quantize + exact integer ||y_q||^2 (+DBIAS for key arithmetic).
__global__ void ysq_cvt_q(const float* __restrict__ Y, float* __restrict__ ysq,
                          int* __restrict__ ysqq, signed char* __restrict__ Yq) {
    int row  = (blockIdx.x * blockDim.x + threadIdx.x) >> 6;
    int lane = threadIdx.x & 63;
    if (row >= NY) return;
    const float4* yr = reinterpret_cast<const float4*>(Y + (size_t)row * DIM);
    signed char* dst = Yq + (size_t)row * DIM;
    double s = 0.0;
    int sq = 0;
#pragma unroll
    for (int i = 0; i < 2; ++i) {
        float4 v = yr[lane + 64 * i];
        s += (double)v.x * v.x + (double)v.y * v.y + (double)v.z * v.z + (double)v.w * v.w;
        int q0 = q24(v.x), q1 = q24(v.y), q2 = q24(v.z), q3 = q24(v.w);
        sq += q0 * q0 + q1 * q1 + q2 * q2 + q3 * q3;
        int packed = (q0 & 255) | ((q1 & 255) << 8) | ((q2 & 255) << 16) | ((q3 & 255) << 24);
        *(int*)(dst + i * 256 + lane * 4) = packed;
    }
#pragma unroll
    for (int off = 32; off > 0; off >>= 1) {
        s  += __shfl_xor(s, off, 64);
        sq += __shfl_xor(sq, off, 64);
    }
    if (lane == 0) { ysq[row] = (float)s; ysqq[row] = sq + DBIAS; }
}

// Coarse: int8 MFMA (16x16x64), r16 geometry (128x128 block, 4x4 frags/wave,
// 0.5 LDS-reads/MFMA, 2 blocks/CU), hierarchical selection: per-stratum top-3
// (3 ops/cand) -> per-chunk top-8 lists.
__global__ __launch_bounds__(256, 2) void knn_coarse_fast(
        const signed char* __restrict__ Xq, const signed char* __restrict__ Yq,
        const int* __restrict__ ysqq,
        unsigned int* __restrict__ cand_k) {
    __shared__ __align__(16) char smem[65536];
    char* As = smem;
    char* Bs = smem + 32768;

    const int tid  = threadIdx.x;
    const int lane = tid & 63;
    const int w    = tid >> 6;
    const int l15  = lane & 15;
    const int lg   = lane >> 4;              // 0..3
    const int xcd  = blockIdx.x;             // 0..7 (linear%8 == blockIdx.x)
    const int s_   = blockIdx.y;             // 0..63
    const int z    = blockIdx.z;             // 0..3
    const int row0  = (xcd * 8 + (s_ & 7)) * BN;   // X tile (8 per XCD resident)
    const int yseg  = s_ >> 3;               // 0..7
    const int ybase = yseg * (NY / NSEG) + z * COLS_PER_CHUNK;
    const int slot  = yseg * NZ + z;         // 0..31 candidate slot
    const int m0 = (w >> 1) * 64;            // wave quadrant: Y side
    const int n0 = (w & 1) * 64;             //                X side

    const int srow = lane >> 3;                     // 0..7
    const int scb  = ((lane & 7) ^ srow) << 4;      // swizzled source chunk
    const char* pXbase = (const char*)Xq
        + ((size_t)(row0 + w * 32 + srow) << 9) + scb;

#define STAGE(tt, kcc, buf)                                                      \
    {                                                                            \
        const char* pY_ = (const char*)Yq                                        \
            + ((size_t)(ybase + (tt) * BM + w * 32 + srow) << 9)                 \
            + ((kcc) << 7) + scb;                                                \
        const char* pX_ = pXbase + ((kcc) << 7);                                 \
        char* dA_ = As + ((buf) << 14) + (w << 12);                              \
        char* dB_ = Bs + ((buf) << 14) + (w << 12);                              \
        _Pragma("unroll")                                                        \
        for (int q = 0; q < 4; ++q) {                                            \
            __builtin_amdgcn_global_load_lds(AS1(pY_ + ((size_t)(q * 8) << 9)),  \
                                             AS3(dA_ + (q << 10)), 16, 0, 0);    \
            __builtin_amdgcn_global_load_lds(AS1(pX_ + ((size_t)(q * 8) << 9)),  \
                                             AS3(dB_ + (q << 10)), 16, 0, 0);    \
        }                                                                        \
    }

    unsigned int kb_[4][LPT];
#pragma unroll
    for (int nf = 0; nf < 4; ++nf)
#pragma unroll
        for (int m = 0; m < LPT; ++m) kb_[nf][m] = 0xffffffffu;

    STAGE(0, 0, 0);   // prologue: 8 loads in flight

    for (int t = 0; t < TILES; ++t) {
        const int ytile0 = ybase + t * BM;

        // biased ysq_q rows (asm: FIFO-tracked; drained by kc=1 vmcnt(0))
        i32x4 yv0, yv1, yv2, yv3;
        {
            const int* yp = ysqq + ytile0 + m0 + lg * 4;
            asm volatile("global_load_dwordx4 %0, %1, off" : "=v"(yv0) : "v"(yp));
            asm volatile("global_load_dwordx4 %0, %1, off" : "=v"(yv1) : "v"(yp + 16));
            asm volatile("global_load_dwordx4 %0, %1, off" : "=v"(yv2) : "v"(yp + 32));
            asm volatile("global_load_dwordx4 %0, %1, off" : "=v"(yv3) : "v"(yp + 48));
        }

        i32x4 acc[4][4];
#pragma unroll
        for (int i = 0; i < 4; ++i)
#pragma unroll
            for (int j = 0; j < 4; ++j) acc[i][j] = (i32x4){0, 0, 0, 0};

#pragma unroll
        for (int kc = 0; kc < KSTEPS; ++kc) {
            const int buf = kc & 1;
            if (kc == 0) asm volatile("s_waitcnt vmcnt(4)" ::: "memory");
            else         asm volatile("s_waitcnt vmcnt(0)" ::: "memory");
            __builtin_amdgcn_sched_barrier(0);
            __builtin_amdgcn_s_barrier();
            if (kc < KSTEPS - 1) {
                STAGE(t, kc + 1, buf ^ 1);
            } else if (t + 1 < TILES) {
                STAGE(t + 1, 0, buf ^ 1);
            }

            const char* Ab = As + (buf << 14);
            const char* Bb = Bs + (buf << 14);
#pragma unroll
            for (int kk = 0; kk < 2; ++kk) {
                const int kbyte = kk * 64 + lg * 16;
                const int sw = kbyte ^ ((l15 & 7) << 4);
                i32x4 af[4], bf[4];
#pragma unroll
                for (int mf = 0; mf < 4; ++mf)
                    af[mf] = *(const i32x4*)(Ab + ((m0 + mf * 16 + l15) << 7) + sw);
#pragma unroll
                for (int nf = 0; nf < 4; ++nf)
                    bf[nf] = *(const i32x4*)(Bb + ((n0 + nf * 16 + l15) << 7) + sw);
                __builtin_amdgcn_s_setprio(1);
#pragma unroll
                for (int mf = 0; mf < 4; ++mf)
#pragma unroll
                    for (int nf = 0; nf < 4; ++nf)
                        acc[mf][nf] = __builtin_amdgcn_mfma_i32_16x16x64_i8(
                            af[mf], bf[nf], acc[mf][nf], 0, 0, 0);
                __builtin_amdgcn_s_setprio(0);
            }
        }

        // epilogue (hierarchical): per nf-stratum (16 cand) keep top-3 in regs
        // (3 ops/cand), then merge the 3 survivors into the chunk top-8 list.
        // key = ((yvb - 2*dot) << 10 & 0xFFFF0000) | gi   (mad_i24 + shl + and_or)
#pragma unroll
        for (int nf = 0; nf < 4; ++nf) {
            unsigned int t0 = 0xffffffffu, t1 = 0xffffffffu, t2 = 0xffffffffu;
#pragma unroll
            for (int mf = 0; mf < 4; ++mf) {
                const i32x4 yv = (mf == 0) ? yv0 : (mf == 1) ? yv1 : (mf == 2) ? yv2 : yv3;
                const int gib = ytile0 + m0 + mf * 16 + lg * 4;
#pragma unroll
                for (int j = 0; j < 4; ++j) {
                    int dqb;
                    asm("v_mad_i32_i24 %0, %1, -2, %2"
                        : "=v"(dqb) : "v"(acc[mf][nf][j]), "v"(yv[j]));
                    unsigned int key = (((unsigned int)dqb << 10) & 0xFFFF0000u)
                                     | (unsigned int)(gib + j);
                    unsigned int n1, n2;
                    asm("v_med3_u32 %0, %1, %2, %3" : "=v"(n1) : "v"(key), "v"(t0), "v"(t1));
                    asm("v_med3_u32 %0, %1, %2, %3" : "=v"(n2) : "v"(key), "v"(t1), "v"(t2));
                    t0 = umin_(t0, key);
                    t1 = n1; t2 = n2;
                }
            }
            pushk_b<LPT>(t0, kb_[nf]);
            pushk_b<LPT>(t1, kb_[nf]);
            pushk_b<LPT>(t2, kb_[nf]);
        }
    }
#undef STAGE

    // ---- merge 8 lane-lists per X row (reuses smem; r16-proven layout) ----
    __syncthreads();
    unsigned int* mbuf = (unsigned int*)smem;   // 128 rows x 66 dwords = 33.8 KB
    const int mslot = (w >> 1) * 4 + lg;        // 0..7
#pragma unroll
    for (int nf = 0; nf < 4; ++nf) {
        const int r = n0 + nf * 16 + l15;
#pragma unroll
        for (int e = 0; e < LPT; ++e)
            mbuf[r * 66 + mslot * LPT + e] = kb_[nf][e];
    }
    __syncthreads();
    if (tid < 128) {
        unsigned int mk[KEEP];
#pragma unroll
        for (int m = 0; m < KEEP; ++m) mk[m] = 0xffffffffu;
        for (int s2 = 0; s2 < 8; ++s2)
#pragma unroll
            for (int e = 0; e < LPT; ++e)
                pushk_b<KEEP>(mbuf[tid * 66 + s2 * LPT + e], mk);
        const int row = row0 + tid;
        unsigned int* co = cand_k + (size_t)row * NCAND + slot * KEEP;
#pragma unroll
        for (int m = 0; m < KEEP; ++m) co[m] = mk[m];
    }
}

// Rescore: coarse top-16 of 256 packed keys, then BIT-EXACT round-1 arithmetic.
__global__ __launch_bounds__(256) void knn_rescore(
        const float* __restrict__ X, const float* __restrict__ Y,
        const float* __restrict__ ysq,
        const unsigned int* __restrict__ cand_k,
        int* __restrict__ out) {
    __shared__ unsigned int ck[16][NCAND];
    __shared__ int   rci[16][RESC];
    __shared__ float rd[16][RESC];

    const int tid  = threadIdx.x;
    const int row0 = blockIdx.x * 16;

#pragma unroll
    for (int q = 0; q < 16; ++q) {
        const int idx = q * 256 + tid;       // 0..4095
        const int r = idx >> 8, j = idx & 255;
        ck[r][j] = cand_k[(size_t)(row0 + r) * NCAND + j];
    }
    __syncthreads();

    if (tid < 16) {
        unsigned int mk[RESC];
#pragma unroll
        for (int m = 0; m < RESC; ++m) mk[m] = 0xffffffffu;
        for (int j = 0; j < NCAND; ++j) pushk<RESC>(ck[tid][j], mk);
#pragma unroll
        for (int m = 0; m < RESC; ++m) rci[tid][m] = (int)(mk[m] & 0xffffu);
    }
    __syncthreads();

    {
        const int r = tid >> 4, c = tid & 15;
        const int row = row0 + r;
        const int yi = rci[r][c];
        const float* xr = X + (size_t)row * DIM;
        const float* yr = Y + (size_t)yi * DIM;
        double acc64 = 0.0;
        for (int kc = 0; kc < DIM; kc += 64) {
            float acc = 0.f;
#pragma unroll
            for (int k4 = 0; k4 < 16; ++k4) {
                float4 xv = *(const float4*)(xr + kc + k4 * 4);
                float4 yv = *(const float4*)(yr + kc + k4 * 4);
                acc = fmaf(xv.x, yv.x, acc);
                acc = fmaf(xv.y, yv.y, acc);
                acc = fmaf(xv.z, yv.z, acc);
                acc = fmaf(xv.w, yv.w, acc);
            }
            acc64 += (double)acc;
        }
        rd[r][c] = (float)((double)ysq[yi] - 2.0 * acc64);
    }
    __syncthreads();

    if (tid < 16) {
        float fd[KNN]; int fi[KNN];
#pragma unroll
        for (int m = 0; m < KNN; ++m) { fd[m] = INFINITY; fi[m] = 0x7fffffff; }
        for (int j = 0; j < RESC; ++j) push<KNN>(rd[tid][j], rci[tid][j], fd, fi);
        const int row = row0 + tid;
#pragma unroll
        for (int m = 0; m < KNN; ++m) out[row * KNN + m] = fi[m];
    }
}

extern "C" void kernel_launch(void* const* d_in, const int* in_sizes, int n_in,
                              void* d_out, int out_size, void* d_ws, size_t ws_size,
                              hipStream_t stream) {
    const float* X = (const float*)d_in[0];   // [8192, 512]
    const float* Y = (const float*)d_in[1];   // [65536, 512]
    int* out = (int*)d_out;                   // [8192, 8] int32

    char* ws = (char*)d_ws;
    float* ysq           = (float*)ws;                              // 256 KB
    int*   ysqq          = (int*)(ws + 262144);                     // 256 KB
    unsigned int* cand_k = (unsigned int*)(ws + 524288);            // 8 MB
    signed char* Xq      = (signed char*)(ws + 524288 + (size_t)NX * NCAND * 4);  // 4 MB
    signed char* Yq      = Xq + (size_t)NX * DIM;                   // 32 MB

    ysq_cvt_q<<<NY / 4, 256, 0, stream>>>(Y, ysq, ysqq, Yq);
    cvt_q_x<<<(NX * DIM / 8) / 256, 256, 0, stream>>>(X, Xq, NX * DIM / 8);

    dim3 g1(8, 64, NZ);   // 2048 blocks; linear%8 = blockIdx.x = xcd
    knn_coarse_fast<<<g1, 256, 0, stream>>>(Xq, Yq, ysqq, cand_k);

    knn_rescore<<<NX / 16, 256, 0, stream>>>(X, Y, ysq, cand_k, out);
}

// Round 19
// 460.705 us; speedup vs baseline: 2.3449x; 1.0170x over previous
//
#include <hip/hip_runtime.h>
#include <math.h>

#define NX 8192
#define NY 65536
#define DIM 512
#define KNN 8

#define BM 128                 // Y rows per tile (MFMA M side)
#define BN 64                  // X rows per block (held in REGISTERS)
#define COLS_PER_CHUNK 2048    // Y rows streamed per block
#define TILES (COLS_PER_CHUNK / BM)           // 16
#define KSTEPS 4               // 512 / 128 (BK = 128 int8 per step)
#define NSEG 8                 // Y segments (s>>4)
#define NZ 4                   // Y sub-segments (grid.z)
#define LPT 8                  // per-lane chunk-level top-K
#define KEEP 8                 // kept per (row, slot)
#define NCAND (NSEG * NZ * KEEP)              // 256 per row
#define RESC 16                // rescored per row
#define QS 24.f                // int8 quantization scale
#define DBIAS (1 << 19)        // key bias: dq always >= 0 after bias

typedef int i32x4 __attribute__((ext_vector_type(4)));

#define AS1(p) (const __attribute__((address_space(1))) void*)(p)
#define AS3(p) (__attribute__((address_space(3))) void*)(p)

__device__ __forceinline__ int q24(float x) {
    float r = rintf(x * QS);
    r = fminf(127.f, fmaxf(-127.f, r));
    return (int)r;
}

__device__ __forceinline__ unsigned int umin_(unsigned int a, unsigned int b) { return a < b ? a : b; }

// branchless sorted-insert (ascending): 1 min + (K-1) med3, no divergence.
template <int K>
__device__ __forceinline__ void pushk_b(unsigned int x, unsigned int (&l)[K]) {
    unsigned int prev = l[0];
    l[0] = umin_(l[0], x);
#pragma unroll
    for (int i = 1; i < K; ++i) {
        unsigned int cur = l[i];
        unsigned int m;
        asm("v_med3_u32 %0, %1, %2, %3" : "=v"(m) : "v"(x), "v"(prev), "v"(cur));
        l[i] = m;
        prev = cur;
    }
}

// branchy insert (serial contexts: cheap reject dominates)
template <int K>
__device__ __forceinline__ void pushk(unsigned int k, unsigned int (&lst)[K]) {
    if (k >= lst[K - 1]) return;
    lst[K - 1] = k;
#pragma unroll
    for (int p = K - 1; p > 0; --p) {
        if (lst[p] < lst[p - 1]) {
            unsigned int t = lst[p]; lst[p] = lst[p - 1]; lst[p - 1] = t;
        }
    }
}

template <int K>
__device__ __forceinline__ void push(float d, int gi, float (&bd)[K], int (&bi)[K]) {
    if (d > bd[K - 1] || (d == bd[K - 1] && gi >= bi[K - 1])) return;
    bd[K - 1] = d; bi[K - 1] = gi;
#pragma unroll
    for (int p = K - 1; p > 0; --p) {
        bool sw = (bd[p] < bd[p - 1]) || (bd[p] == bd[p - 1] && bi[p] < bi[p - 1]);
        if (sw) {
            float td = bd[p]; bd[p] = bd[p - 1]; bd[p - 1] = td;
            int   ti = bi[p]; bi[p] = bi[p - 1]; bi[p - 1] = ti;
        }
    }
}

// X: quantize 8 elems/thread to int8
__global__ void cvt_q_x(const float* __restrict__ src, signed char* __restrict__ dst, int n8) {
    int i = blockIdx.x * blockDim.x + threadIdx.x;
    if (i >= n8) return;
    const float4* s = (const float4*)src;
    float4 a0 = s[i * 2], a1 = s[i * 2 + 1];
    int lo = (q24(a0.x) & 255) | ((q24(a0.y) & 255) << 8)
           | ((q24(a0.z) & 255) << 16) | ((q24(a0.w) & 255) << 24);
    int hi = (q24(a1.x) & 255) | ((q24(a1.y) & 255) << 8)
           | ((q24(a1.z) & 255) << 16) | ((q24(a1.w) & 255) << 24);
    int2 v; v.x = lo; v.y = hi;
    *(int2*)(dst + (size_t)i * 8) = v;
}

// Fused per Y row: fp64 ysq (EXACT round-1 summation order, bit-identical) +
// int8 quantize + exact integer ||y_q||^2 (+DBIAS for key arithmetic).
__global__ void ysq_cvt_q(const float* __restrict__ Y, float* __restrict__ ysq,
                          int* __restrict__ ysqq, signed char* __restrict__ Yq) {
    int row  = (blockIdx.x * blockDim.x + threadIdx.x) >> 6;
    int lane = threadIdx.x & 63;
    if (row >= NY) return;
    const float4* yr = reinterpret_cast<const float4*>(Y + (size_t)row * DIM);
    signed char* dst = Yq + (size_t)row * DIM;
    double s = 0.0;
    int sq = 0;
#pragma unroll
    for (int i = 0; i < 2; ++i) {
        float4 v = yr[lane + 64 * i];
        s += (double)v.x * v.x + (double)v.y * v.y + (double)v.z * v.z + (double)v.w * v.w;
        int q0 = q24(v.x), q1 = q24(v.y), q2 = q24(v.z), q3 = q24(v.w);
        sq += q0 * q0 + q1 * q1 + q2 * q2 + q3 * q3;
        int packed = (q0 & 255) | ((q1 & 255) << 8) | ((q2 & 255) << 16) | ((q3 & 255) << 24);
        *(int*)(dst + i * 256 + lane * 4) = packed;
    }
#pragma unroll
    for (int off = 32; off > 0; off >>= 1) {
        s  += __shfl_xor(s, off, 64);
        sq += __shfl_xor(sq, off, 64);
    }
    if (lane == 0) { ysq[row] = (float)s; ysqq[row] = sq + DBIAS; }
}

// Coarse: int8 MFMA, X operand in REGISTERS (64 VGPR/lane, loaded once from
// global), LDS holds only the Y double-buffer (32 KB -> 3 blocks/CU).
// Hierarchical selection: per-stratum top-3 -> per-chunk top-8 lists.
__global__ __launch_bounds__(256, 3) void knn_coarse_fast(
        const signed char* __restrict__ Xq, const signed char* __restrict__ Yq,
        const int* __restrict__ ysqq,
        unsigned int* __restrict__ cand_k) {
    __shared__ __align__(16) char smem[32768];   // As dbuf: 2 x [128 rows][128 B]
    char* As = smem;

    const int tid  = threadIdx.x;
    const int lane = tid & 63;
    const int w    = tid >> 6;
    const int l15  = lane & 15;
    const int lg   = lane >> 4;              // 0..3
    const int xcd  = blockIdx.x;             // 0..7 (linear%8 == blockIdx.x)
    const int s_   = blockIdx.y;             // 0..127
    const int z    = blockIdx.z;             // 0..3
    const int row0  = (xcd * 16 + (s_ & 15)) * BN;  // X tile (16/XCD = 512 KB)
    const int yseg  = s_ >> 4;               // 0..7
    const int ybase = yseg * (NY / NSEG) + z * COLS_PER_CHUNK;
    const int slot  = yseg * NZ + z;         // 0..31 candidate slot
    const int m0 = (w >> 1) * 64;            // wave quadrant: Y side (2-way)
    const int n0 = (w & 1) * 32;             //                X side (2-way)

    // ---- X fragments -> registers, once (unswizzled: direct global read) ----
    // frag(nf,kc,kk): X[row0+n0+nf*16+l15][byte kc*128 + kk*64 + lg*16 .. +16]
    i32x4 xf[2][4][2];
    {
        const char* xb = (const char*)Xq + ((size_t)(row0 + n0 + l15) << 9) + lg * 16;
#pragma unroll
        for (int nf = 0; nf < 2; ++nf)
#pragma unroll
            for (int kc = 0; kc < 4; ++kc)
#pragma unroll
                for (int kk = 0; kk < 2; ++kk)
                    xf[nf][kc][kk] = *(const i32x4*)(xb + (nf << 13) + kc * 128 + kk * 64);
    }

    const int srow = lane >> 3;                     // 0..7
    const int scb  = ((lane & 7) ^ srow) << 4;      // swizzled source chunk

#define STAGE(tt, kcc, buf)                                                      \
    {                                                                            \
        const char* pY_ = (const char*)Yq                                        \
            + ((size_t)(ybase + (tt) * BM + w * 32 + srow) << 9)                 \
            + ((kcc) << 7) + scb;                                                \
        char* dA_ = As + ((buf) << 14) + (w << 12);                              \
        _Pragma("unroll")                                                        \
        for (int q = 0; q < 4; ++q)                                              \
            __builtin_amdgcn_global_load_lds(AS1(pY_ + ((size_t)(q * 8) << 9)),  \
                                             AS3(dA_ + (q << 10)), 16, 0, 0);    \
    }

    unsigned int kb_[2][LPT];
#pragma unroll
    for (int nf = 0; nf < 2; ++nf)
#pragma unroll
        for (int m = 0; m < LPT; ++m) kb_[nf][m] = 0xffffffffu;

    STAGE(0, 0, 0);   // prologue: 4 loads in flight (after the 16 xf loads)

    for (int t = 0; t < TILES; ++t) {
        const int ytile0 = ybase + t * BM;

        // biased ysq_q rows (asm: FIFO-tracked; drained by kc=1 vmcnt(0))
        i32x4 yv0, yv1, yv2, yv3;
        {
            const int* yp = ysqq + ytile0 + m0 + lg * 4;
            asm volatile("global_load_dwordx4 %0, %1, off" : "=v"(yv0) : "v"(yp));
            asm volatile("global_load_dwordx4 %0, %1, off" : "=v"(yv1) : "v"(yp + 16));
            asm volatile("global_load_dwordx4 %0, %1, off" : "=v"(yv2) : "v"(yp + 32));
            asm volatile("global_load_dwordx4 %0, %1, off" : "=v"(yv3) : "v"(yp + 48));
        }

        i32x4 acc[4][2];
#pragma unroll
        for (int i = 0; i < 4; ++i)
#pragma unroll
            for (int j = 0; j < 2; ++j) acc[i][j] = (i32x4){0, 0, 0, 0};

#pragma unroll
        for (int kc = 0; kc < KSTEPS; ++kc) {
            const int buf = kc & 1;
            // kc==0: [stage(t,0):4, ysq:4] -> vmcnt(4) keeps ysq in flight.
            if (kc == 0) asm volatile("s_waitcnt vmcnt(4)" ::: "memory");
            else         asm volatile("s_waitcnt vmcnt(0)" ::: "memory");
            __builtin_amdgcn_sched_barrier(0);
            __builtin_amdgcn_s_barrier();
            if (kc < KSTEPS - 1) {
                STAGE(t, kc + 1, buf ^ 1);
            } else if (t + 1 < TILES) {
                STAGE(t + 1, 0, buf ^ 1);
            }

            const char* Ab = As + (buf << 14);
#pragma unroll
            for (int kk = 0; kk < 2; ++kk) {
                const int kbyte = kk * 64 + lg * 16;
                const int sw = kbyte ^ ((l15 & 7) << 4);
                i32x4 af[4];
#pragma unroll
                for (int mf = 0; mf < 4; ++mf)
                    af[mf] = *(const i32x4*)(Ab + ((m0 + mf * 16 + l15) << 7) + sw);
                __builtin_amdgcn_s_setprio(1);
#pragma unroll
                for (int mf = 0; mf < 4; ++mf)
#pragma unroll
                    for (int nf = 0; nf < 2; ++nf)
                        acc[mf][nf] = __builtin_amdgcn_mfma_i32_16x16x64_i8(
                            af[mf], xf[nf][kc][kk], acc[mf][nf], 0, 0, 0);
                __builtin_amdgcn_s_setprio(0);
            }
        }

        // epilogue (hierarchical): per nf-stratum (16 cand) top-3 in regs,
        // then merge survivors into the chunk top-8 list.
#pragma unroll
        for (int nf = 0; nf < 2; ++nf) {
            unsigned int t0 = 0xffffffffu, t1 = 0xffffffffu, t2 = 0xffffffffu;
#pragma unroll
            for (int mf = 0; mf < 4; ++mf) {
                const i32x4 yv = (mf == 0) ? yv0 : (mf == 1) ? yv1 : (mf == 2) ? yv2 : yv3;
                const int gib = ytile0 + m0 + mf * 16 + lg * 4;
#pragma unroll
                for (int j = 0; j < 4; ++j) {
                    int dqb;
                    asm("v_mad_i32_i24 %0, %1, -2, %2"
                        : "=v"(dqb) : "v"(acc[mf][nf][j]), "v"(yv[j]));
                    unsigned int key = (((unsigned int)dqb << 10) & 0xFFFF0000u)
                                     | (unsigned int)(gib + j);
                    unsigned int n1, n2;
                    asm("v_med3_u32 %0, %1, %2, %3" : "=v"(n1) : "v"(key), "v"(t0), "v"(t1));
                    asm("v_med3_u32 %0, %1, %2, %3" : "=v"(n2) : "v"(key), "v"(t1), "v"(t2));
                    t0 = umin_(t0, key);
                    t1 = n1; t2 = n2;
                }
            }
            pushk_b<LPT>(t0, kb_[nf]);
            pushk_b<LPT>(t1, kb_[nf]);
            pushk_b<LPT>(t2, kb_[nf]);
        }
    }
#undef STAGE

    // ---- merge 8 lane-lists per X row (reuses smem) ----
    __syncthreads();
    unsigned int* mbuf = (unsigned int*)smem;   // 64 rows x 66 dwords = 16.9 KB
    const int mslot = (w >> 1) * 4 + lg;        // 0..7
#pragma unroll
    for (int nf = 0; nf < 2; ++nf) {
        const int r = n0 + nf * 16 + l15;       // 0..63
#pragma unroll
        for (int e = 0; e < LPT; ++e)
            mbuf[r * 66 + mslot * LPT + e] = kb_[nf][e];
    }
    __syncthreads();
    if (tid < 64) {
        unsigned int mk[KEEP];
#pragma unroll
        for (int m = 0; m < KEEP; ++m) mk[m] = 0xffffffffu;
        for (int s2 = 0; s2 < 8; ++s2)
#pragma unroll
            for (int e = 0; e < LPT; ++e)
                pushk_b<KEEP>(mbuf[tid * 66 + s2 * LPT + e], mk);
        const int row = row0 + tid;
        unsigned int* co = cand_k + (size_t)row * NCAND + slot * KEEP;
#pragma unroll
        for (int m = 0; m < KEEP; ++m) co[m] = mk[m];
    }
}

// Rescore: coarse top-16 of 256 packed keys, then BIT-EXACT round-1 arithmetic.
// X rows staged once in LDS (same bits -> same fp32 ops -> bit-exact).
__global__ __launch_bounds__(256) void knn_rescore(
        const float* __restrict__ X, const float* __restrict__ Y,
        const float* __restrict__ ysq,
        const unsigned int* __restrict__ cand_k,
        int* __restrict__ out) {
    __shared__ unsigned int ck[16][NCAND];               // 16 KB
    __shared__ int   rci[16][RESC];
    __shared__ float rd[16][RESC];
    __shared__ __align__(16) float xs[16][516];          // 33 KB (pad 4)

    const int tid  = threadIdx.x;
    const int row0 = blockIdx.x * 16;

    // stage 16 X rows (coalesced float4)
#pragma unroll
    for (int q = 0; q < 8; ++q) {
        const int fidx = q * 256 + tid;      // 0..2047 float4 units
        const int r = fidx >> 7, c4 = fidx & 127;
        *(float4*)&xs[r][c4 * 4] = *(const float4*)(X + (size_t)(row0 + r) * DIM + c4 * 4);
    }
#pragma unroll
    for (int q = 0; q < 16; ++q) {
        const int idx = q * 256 + tid;       // 0..4095
        const int r = idx >> 8, j = idx & 255;
        ck[r][j] = cand_k[(size_t)(row0 + r) * NCAND + j];
    }
    __syncthreads();

    if (tid < 16) {
        unsigned int mk[RESC];
#pragma unroll
        for (int m = 0; m < RESC; ++m) mk[m] = 0xffffffffu;
        for (int j = 0; j < NCAND; ++j) pushk<RESC>(ck[tid][j], mk);
#pragma unroll
        for (int m = 0; m < RESC; ++m) rci[tid][m] = (int)(mk[m] & 0xffffu);
    }
    __syncthreads();

    {
        const int r = tid >> 4, c = tid & 15;
        const int yi = rci[r][c];
        const float* xr = xs[r];
        const float* yr = Y + (size_t)yi * DIM;
        double acc64 = 0.0;
        for (int kc = 0; kc < DIM; kc += 64) {
            float acc = 0.f;
#pragma unroll
            for (int k4 = 0; k4 < 16; ++k4) {
                float4 xv = *(const float4*)(xr + kc + k4 * 4);
                float4 yv = *(const float4*)(yr + kc + k4 * 4);
                acc = fmaf(xv.x, yv.x, acc);
                acc = fmaf(xv.y, yv.y, acc);
                acc = fmaf(xv.z, yv.z, acc);
                acc = fmaf(xv.w, yv.w, acc);
            }
            acc64 += (double)acc;
        }
        rd[r][c] = (float)((double)ysq[yi] - 2.0 * acc64);
    }
    __syncthreads();

    if (tid < 16) {
        float fd[KNN]; int fi[KNN];
#pragma unroll
        for (int m = 0; m < KNN; ++m) { fd[m] = INFINITY; fi[m] = 0x7fffffff; }
        for (int j = 0; j < RESC; ++j) push<KNN>(rd[tid][j], rci[tid][j], fd, fi);
        const int row = row0 + tid;
#pragma unroll
        for (int m = 0; m < KNN; ++m) out[row * KNN + m] = fi[m];
    }
}

extern "C" void kernel_launch(void* const* d_in, const int* in_sizes, int n_in,
                              void* d_out, int out_size, void* d_ws, size_t ws_size,
                              hipStream_t stream) {
    const float* X = (const float*)d_in[0];   // [8192, 512]
    const float* Y = (const float*)d_in[1];   // [65536, 512]
    int* out = (int*)d_out;                   // [8192, 8] int32

    char* ws = (char*)d_ws;
    float* ysq           = (float*)ws;                              // 256 KB
    int*   ysqq          = (int*)(ws + 262144);                     // 256 KB
    unsigned int* cand_k = (unsigned int*)(ws + 524288);            // 8 MB
    signed char* Xq      = (signed char*)(ws + 524288 + (size_t)NX * NCAND * 4);  // 4 MB
    signed char* Yq      = Xq + (size_t)NX * DIM;                   // 32 MB

    ysq_cvt_q<<<NY / 4, 256, 0, stream>>>(Y, ysq, ysqq, Yq);
    cvt_q_x<<<(NX * DIM / 8) / 256, 256, 0, stream>>>(X, Xq, NX * DIM / 8);

    dim3 g1(8, 128, NZ);   // 4096 blocks; linear%8 = blockIdx.x = xcd
    knn_coarse_fast<<<g1, 256, 0, stream>>>(Xq, Yq, ysqq, cand_k);

    knn_rescore<<<NX / 16, 256, 0, stream>>>(X, Y, ysq, cand_k, out);
}

// Round 20
// 452.357 us; speedup vs baseline: 2.3882x; 1.0185x over previous
//
#include <hip/hip_runtime.h>
#include <math.h>

#define NX 8192
#define NY 65536
#define DIM 512
#define KNN 8

#define BM 128                 // Y rows per tile (MFMA M side)
#define BN 128                 // X rows per block (MFMA N side)
#define COLS_PER_CHUNK 2048    // Y rows streamed per block
#define TILES (COLS_PER_CHUNK / BM)           // 16
#define KSTEPS 4               // 512 / 128 (BK = 128 int8 per step)
#define NSEG 8                 // Y segments (s>>3)
#define NZ 4                   // Y sub-segments (grid.z)
#define LPT 8                  // per-lane chunk-level top-K
#define KEEP 8                 // kept per (row, slot)
#define NCAND (NSEG * NZ * KEEP)              // 256 per row
#define RESC 16                // rescored per row
#define QS 24.f                // int8 quantization scale
#define DBIAS (1 << 19)        // key bias: dq always >= 0 after bias

typedef int i32x4 __attribute__((ext_vector_type(4)));

#define AS1(p) (const __attribute__((address_space(1))) void*)(p)
#define AS3(p) (__attribute__((address_space(3))) void*)(p)

__device__ __forceinline__ int q24(float x) {
    float r = rintf(x * QS);
    r = fminf(127.f, fmaxf(-127.f, r));
    return (int)r;
}

__device__ __forceinline__ unsigned int umin_(unsigned int a, unsigned int b) { return a < b ? a : b; }

// branchless sorted-insert (ascending): 1 min + (K-1) med3, no divergence.
template <int K>
__device__ __forceinline__ void pushk_b(unsigned int x, unsigned int (&l)[K]) {
    unsigned int prev = l[0];
    l[0] = umin_(l[0], x);
#pragma unroll
    for (int i = 1; i < K; ++i) {
        unsigned int cur = l[i];
        unsigned int m;
        asm("v_med3_u32 %0, %1, %2, %3" : "=v"(m) : "v"(x), "v"(prev), "v"(cur));
        l[i] = m;
        prev = cur;
    }
}

// branchy insert (serial contexts: cheap reject dominates)
template <int K>
__device__ __forceinline__ void pushk(unsigned int k, unsigned int (&lst)[K]) {
    if (k >= lst[K - 1]) return;
    lst[K - 1] = k;
#pragma unroll
    for (int p = K - 1; p > 0; --p) {
        if (lst[p] < lst[p - 1]) {
            unsigned int t = lst[p]; lst[p] = lst[p - 1]; lst[p - 1] = t;
        }
    }
}

template <int K>
__device__ __forceinline__ void push(float d, int gi, float (&bd)[K], int (&bi)[K]) {
    if (d > bd[K - 1] || (d == bd[K - 1] && gi >= bi[K - 1])) return;
    bd[K - 1] = d; bi[K - 1] = gi;
#pragma unroll
    for (int p = K - 1; p > 0; --p) {
        bool sw = (bd[p] < bd[p - 1]) || (bd[p] == bd[p - 1] && bi[p] < bi[p - 1]);
        if (sw) {
            float td = bd[p]; bd[p] = bd[p - 1]; bd[p - 1] = td;
            int   ti = bi[p]; bi[p] = bi[p - 1]; bi[p - 1] = ti;
        }
    }
}

// X: quantize 8 elems/thread to int8
__global__ void cvt_q_x(const float* __restrict__ src, signed char* __restrict__ dst, int n8) {
    int i = blockIdx.x * blockDim.x + threadIdx.x;
    if (i >= n8) return;
    const float4* s = (const float4*)src;
    float4 a0 = s[i * 2], a1 = s[i * 2 + 1];
    int lo = (q24(a0.x) & 255) | ((q24(a0.y) & 255) << 8)
           | ((q24(a0.z) & 255) << 16) | ((q24(a0.w) & 255) << 24);
    int hi = (q24(a1.x) & 255) | ((q24(a1.y) & 255) << 8)
           | ((q24(a1.z) & 255) << 16) | ((q24(a1.w) & 255) << 24);
    int2 v; v.x = lo; v.y = hi;
    *(int2*)(dst + (size_t)i * 8) = v;
}

// Fused per Y row: fp64 ysq (EXACT round-1 summation order, bit-identical) +
// int8 quantize + exact integer ||y_q||^2 (+DBIAS for key arithmetic).
__global__ void ysq_cvt_q(const float* __restrict__ Y, float* __restrict__ ysq,
                          int* __restrict__ ysqq, signed char* __restrict__ Yq) {
    int row  = (blockIdx.x * blockDim.x + threadIdx.x) >> 6;
    int lane = threadIdx.x & 63;
    if (row >= NY) return;
    const float4* yr = reinterpret_cast<const float4*>(Y + (size_t)row * DIM);
    signed char* dst = Yq + (size_t)row * DIM;
    double s = 0.0;
    int sq = 0;
#pragma unroll
    for (int i = 0; i < 2; ++i) {
        float4 v = yr[lane + 64 * i];
        s += (double)v.x * v.x + (double)v.y * v.y + (double)v.z * v.z + (double)v.w * v.w;
        int q0 = q24(v.x), q1 = q24(v.y), q2 = q24(v.z), q3 = q24(v.w);
        sq += q0 * q0 + q1 * q1 + q2 * q2 + q3 * q3;
        int packed = (q0 & 255) | ((q1 & 255) << 8) | ((q2 & 255) << 16) | ((q3 & 255) << 24);
        *(int*)(dst + i * 256 + lane * 4) = packed;
    }
#pragma unroll
    for (int off = 32; off > 0; off >>= 1) {
        s  += __shfl_xor(s, off, 64);
        sq += __shfl_xor(sq, off, 64);
    }
    if (lane == 0) { ysq[row] = (float)s; ysqq[row] = sq + DBIAS; }
}

// Coarse (r18, proven 354 us): int8 MFMA 16x16x64, 128x128 block, 4x4
// frags/wave (0.5 LDS-reads/MFMA), dbuf As+Bs, one barrier per K-step,
// hierarchical per-stratum top-3 -> per-chunk top-8 packed-key lists.
__global__ __launch_bounds__(256, 2) void knn_coarse_fast(
        const signed char* __restrict__ Xq, const signed char* __restrict__ Yq,
        const int* __restrict__ ysqq,
        unsigned int* __restrict__ cand_k) {
    __shared__ __align__(16) char smem[65536];
    char* As = smem;
    char* Bs = smem + 32768;

    const int tid  = threadIdx.x;
    const int lane = tid & 63;
    const int w    = tid >> 6;
    const int l15  = lane & 15;
    const int lg   = lane >> 4;              // 0..3
    const int xcd  = blockIdx.x;             // 0..7 (linear%8 == blockIdx.x)
    const int s_   = blockIdx.y;             // 0..63
    const int z    = blockIdx.z;             // 0..3
    const int row0  = (xcd * 8 + (s_ & 7)) * BN;   // X tile (8 per XCD resident)
    const int yseg  = s_ >> 3;               // 0..7
    const int ybase = yseg * (NY / NSEG) + z * COLS_PER_CHUNK;
    const int slot  = yseg * NZ + z;         // 0..31 candidate slot
    const int m0 = (w >> 1) * 64;            // wave quadrant: Y side
    const int n0 = (w & 1) * 64;             //                X side

    const int srow = lane >> 3;                     // 0..7
    const int scb  = ((lane & 7) ^ srow) << 4;      // swizzled source chunk
    const char* pXbase = (const char*)Xq
        + ((size_t)(row0 + w * 32 + srow) << 9) + scb;

#define STAGE(tt, kcc, buf)                                                      \
    {                                                                            \
        const char* pY_ = (const char*)Yq                                        \
            + ((size_t)(ybase + (tt) * BM + w * 32 + srow) << 9)                 \
            + ((kcc) << 7) + scb;                                                \
        const char* pX_ = pXbase + ((kcc) << 7);                                 \
        char* dA_ = As + ((buf) << 14) + (w << 12);                              \
        char* dB_ = Bs + ((buf) << 14) + (w << 12);                              \
        _Pragma("unroll")                                                        \
        for (int q = 0; q < 4; ++q) {                                            \
            __builtin_amdgcn_global_load_lds(AS1(pY_ + ((size_t)(q * 8) << 9)),  \
                                             AS3(dA_ + (q << 10)), 16, 0, 0);    \
            __builtin_amdgcn_global_load_lds(AS1(pX_ + ((size_t)(q * 8) << 9)),  \
                                             AS3(dB_ + (q << 10)), 16, 0, 0);    \
        }                                                                        \
    }

    unsigned int kb_[4][LPT];
#pragma unroll
    for (int nf = 0; nf < 4; ++nf)
#pragma unroll
        for (int m = 0; m < LPT; ++m) kb_[nf][m] = 0xffffffffu;

    STAGE(0, 0, 0);   // prologue: 8 loads in flight

    for (int t = 0; t < TILES; ++t) {
        const int ytile0 = ybase + t * BM;

        // biased ysq_q rows (asm: FIFO-tracked; drained by kc=1 vmcnt(0))
        i32x4 yv0, yv1, yv2, yv3;
        {
            const int* yp = ysqq + ytile0 + m0 + lg * 4;
            asm volatile("global_load_dwordx4 %0, %1, off" : "=v"(yv0) : "v"(yp));
            asm volatile("global_load_dwordx4 %0, %1, off" : "=v"(yv1) : "v"(yp + 16));
            asm volatile("global_load_dwordx4 %0, %1, off" : "=v"(yv2) : "v"(yp + 32));
            asm volatile("global_load_dwordx4 %0, %1, off" : "=v"(yv3) : "v"(yp + 48));
        }

        i32x4 acc[4][4];
#pragma unroll
        for (int i = 0; i < 4; ++i)
#pragma unroll
            for (int j = 0; j < 4; ++j) acc[i][j] = (i32x4){0, 0, 0, 0};

#pragma unroll
        for (int kc = 0; kc < KSTEPS; ++kc) {
            const int buf = kc & 1;
            if (kc == 0) asm volatile("s_waitcnt vmcnt(4)" ::: "memory");
            else         asm volatile("s_waitcnt vmcnt(0)" ::: "memory");
            __builtin_amdgcn_sched_barrier(0);
            __builtin_amdgcn_s_barrier();
            if (kc < KSTEPS - 1) {
                STAGE(t, kc + 1, buf ^ 1);
            } else if (t + 1 < TILES) {
                STAGE(t + 1, 0, buf ^ 1);
            }

            const char* Ab = As + (buf << 14);
            const char* Bb = Bs + (buf << 14);
#pragma unroll
            for (int kk = 0; kk < 2; ++kk) {
                const int kbyte = kk * 64 + lg * 16;
                const int sw = kbyte ^ ((l15 & 7) << 4);
                i32x4 af[4], bf[4];
#pragma unroll
                for (int mf = 0; mf < 4; ++mf)
                    af[mf] = *(const i32x4*)(Ab + ((m0 + mf * 16 + l15) << 7) + sw);
#pragma unroll
                for (int nf = 0; nf < 4; ++nf)
                    bf[nf] = *(const i32x4*)(Bb + ((n0 + nf * 16 + l15) << 7) + sw);
                __builtin_amdgcn_s_setprio(1);
#pragma unroll
                for (int mf = 0; mf < 4; ++mf)
#pragma unroll
                    for (int nf = 0; nf < 4; ++nf)
                        acc[mf][nf] = __builtin_amdgcn_mfma_i32_16x16x64_i8(
                            af[mf], bf[nf], acc[mf][nf], 0, 0, 0);
                __builtin_amdgcn_s_setprio(0);
            }
        }

        // epilogue (hierarchical): per nf-stratum (16 cand) keep top-3 in regs
        // (1 min + 2 med3 per cand), then merge survivors into chunk top-8.
        // key = ((yvb - 2*dot) << 10 & 0xFFFF0000) | gi
#pragma unroll
        for (int nf = 0; nf < 4; ++nf) {
            unsigned int t0 = 0xffffffffu, t1 = 0xffffffffu, t2 = 0xffffffffu;
#pragma unroll
            for (int mf = 0; mf < 4; ++mf) {
                const i32x4 yv = (mf == 0) ? yv0 : (mf == 1) ? yv1 : (mf == 2) ? yv2 : yv3;
                const int gib = ytile0 + m0 + mf * 16 + lg * 4;
#pragma unroll
                for (int j = 0; j < 4; ++j) {
                    int dqb;
                    asm("v_mad_i32_i24 %0, %1, -2, %2"
                        : "=v"(dqb) : "v"(acc[mf][nf][j]), "v"(yv[j]));
                    unsigned int key = (((unsigned int)dqb << 10) & 0xFFFF0000u)
                                     | (unsigned int)(gib + j);
                    unsigned int n1, n2;
                    asm("v_med3_u32 %0, %1, %2, %3" : "=v"(n1) : "v"(key), "v"(t0), "v"(t1));
                    asm("v_med3_u32 %0, %1, %2, %3" : "=v"(n2) : "v"(key), "v"(t1), "v"(t2));
                    t0 = umin_(t0, key);
                    t1 = n1; t2 = n2;
                }
            }
            pushk_b<LPT>(t0, kb_[nf]);
            pushk_b<LPT>(t1, kb_[nf]);
            pushk_b<LPT>(t2, kb_[nf]);
        }
    }
#undef STAGE

    // ---- merge 8 lane-lists per X row (reuses smem) ----
    __syncthreads();
    unsigned int* mbuf = (unsigned int*)smem;   // 128 rows x 66 dwords = 33.8 KB
    const int mslot = (w >> 1) * 4 + lg;        // 0..7
#pragma unroll
    for (int nf = 0; nf < 4; ++nf) {
        const int r = n0 + nf * 16 + l15;
#pragma unroll
        for (int e = 0; e < LPT; ++e)
            mbuf[r * 66 + mslot * LPT + e] = kb_[nf][e];
    }
    __syncthreads();
    if (tid < 128) {
        unsigned int mk[KEEP];
#pragma unroll
        for (int m = 0; m < KEEP; ++m) mk[m] = 0xffffffffu;
        for (int s2 = 0; s2 < 8; ++s2)
#pragma unroll
            for (int e = 0; e < LPT; ++e)
                pushk_b<KEEP>(mbuf[tid * 66 + s2 * LPT + e], mk);
        const int row = row0 + tid;
        unsigned int* co = cand_k + (size_t)row * NCAND + slot * KEEP;
#pragma unroll
        for (int m = 0; m < KEEP; ++m) co[m] = mk[m];
    }
}

// Rescore (r19, proven): coarse top-16 of 256 packed keys, X rows staged in
// LDS (bit-identical data), then BIT-EXACT round-1 fp32/fp64 arithmetic.
__global__ __launch_bounds__(256) void knn_rescore(
        const float* __restrict__ X, const float* __restrict__ Y,
        const float* __restrict__ ysq,
        const unsigned int* __restrict__ cand_k,
        int* __restrict__ out) {
    __shared__ unsigned int ck[16][NCAND];               // 16 KB
    __shared__ int   rci[16][RESC];
    __shared__ float rd[16][RESC];
    __shared__ __align__(16) float xs[16][516];          // 33 KB (pad 4)

    const int tid  = threadIdx.x;
    const int row0 = blockIdx.x * 16;

    // stage 16 X rows (coalesced float4)
#pragma unroll
    for (int q = 0; q < 8; ++q) {
        const int fidx = q * 256 + tid;      // 0..2047 float4 units
        const int r = fidx >> 7, c4 = fidx & 127;
        *(float4*)&xs[r][c4 * 4] = *(const float4*)(X + (size_t)(row0 + r) * DIM + c4 * 4);
    }
#pragma unroll
    for (int q = 0; q < 16; ++q) {
        const int idx = q * 256 + tid;       // 0..4095
        const int r = idx >> 8, j = idx & 255;
        ck[r][j] = cand_k[(size_t)(row0 + r) * NCAND + j];
    }
    __syncthreads();

    if (tid < 16) {
        unsigned int mk[RESC];
#pragma unroll
        for (int m = 0; m < RESC; ++m) mk[m] = 0xffffffffu;
        for (int j = 0; j < NCAND; ++j) pushk<RESC>(ck[tid][j], mk);
#pragma unroll
        for (int m = 0; m < RESC; ++m) rci[tid][m] = (int)(mk[m] & 0xffffu);
    }
    __syncthreads();

    {
        const int r = tid >> 4, c = tid & 15;
        const int yi = rci[r][c];
        const float* xr = xs[r];
        const float* yr = Y + (size_t)yi * DIM;
        double acc64 = 0.0;
        for (int kc = 0; kc < DIM; kc += 64) {
            float acc = 0.f;
#pragma unroll
            for (int k4 = 0; k4 < 16; ++k4) {
                float4 xv = *(const float4*)(xr + kc + k4 * 4);
                float4 yv = *(const float4*)(yr + kc + k4 * 4);
                acc = fmaf(xv.x, yv.x, acc);
                acc = fmaf(xv.y, yv.y, acc);
                acc = fmaf(xv.z, yv.z, acc);
                acc = fmaf(xv.w, yv.w, acc);
            }
            acc64 += (double)acc;
        }
        rd[r][c] = (float)((double)ysq[yi] - 2.0 * acc64);
    }
    __syncthreads();

    if (tid < 16) {
        float fd[KNN]; int fi[KNN];
#pragma unroll
        for (int m = 0; m < KNN; ++m) { fd[m] = INFINITY; fi[m] = 0x7fffffff; }
        for (int j = 0; j < RESC; ++j) push<KNN>(rd[tid][j], rci[tid][j], fd, fi);
        const int row = row0 + tid;
#pragma unroll
        for (int m = 0; m < KNN; ++m) out[row * KNN + m] = fi[m];
    }
}

extern "C" void kernel_launch(void* const* d_in, const int* in_sizes, int n_in,
                              void* d_out, int out_size, void* d_ws, size_t ws_size,
                              hipStream_t stream) {
    const float* X = (const float*)d_in[0];   // [8192, 512]
    const float* Y = (const float*)d_in[1];   // [65536, 512]
    int* out = (int*)d_out;                   // [8192, 8] int32

    char* ws = (char*)d_ws;
    float* ysq           = (float*)ws;                              // 256 KB
    int*   ysqq          = (int*)(ws + 262144);                     // 256 KB
    unsigned int* cand_k = (unsigned int*)(ws + 524288);            // 8 MB
    signed char* Xq      = (signed char*)(ws + 524288 + (size_t)NX * NCAND * 4);  // 4 MB
    signed char* Yq      = Xq + (size_t)NX * DIM;                   // 32 MB

    ysq_cvt_q<<<NY / 4, 256, 0, stream>>>(Y, ysq, ysqq, Yq);
    cvt_q_x<<<(NX * DIM / 8) / 256, 256, 0, stream>>>(X, Xq, NX * DIM / 8);

    dim3 g1(8, 64, NZ);   // 2048 blocks; linear%8 = blockIdx.x = xcd
    knn_coarse_fast<<<g1, 256, 0, stream>>>(Xq, Yq, ysqq, cand_k);

    knn_rescore<<<NX / 16, 256, 0, stream>>>(X, Y, ysq, cand_k, out);
}